// Round 8
// baseline (1826.942 us; speedup 1.0000x reference)
//
#include <hip/hip_runtime.h>
#include <hip/hip_bf16.h>

// ---------------------------------------------------------------------------
// VGG16 perceptual+style inpainting loss.
// conv2..7: bf16 MFMA NHWC on ZERO-PADDED buffers ([n][H+2][W+2][C]) with
// global_load_lds (width 16) staging (m97 recipe). conv2/4/7 fuse 2x2 maxpool
// in-register. B-weights direct from global. conv1 fp32-direct -> padded NHWC.
// Gram: bf16 MFMA on col-major planar (transpose_k). l1/perc grid-stride.
// Workspace: 3.3MB weights + NB*97.4MB; NB=2 needs 198.3MB, NB=1 100.9MB.
// ---------------------------------------------------------------------------

typedef __attribute__((ext_vector_type(8))) short bf16x8_t;
typedef __attribute__((ext_vector_type(4))) float f32x4_t;

typedef __attribute__((address_space(3))) unsigned int lds_uint_t;
typedef __attribute__((address_space(1))) const unsigned int glob_uint_t;

__device__ __forceinline__ void async16(const void* g, void* l) {
  __builtin_amdgcn_global_load_lds((glob_uint_t*)g, (lds_uint_t*)l, 16, 0, 0);
}

__device__ __forceinline__ float b2f(__hip_bfloat16 v) {
  return __bfloat162float(v);
}

__device__ __forceinline__ float blk_sum256(float v, float* s4) {
#pragma unroll
  for (int o = 32; o > 0; o >>= 1) v += __shfl_down(v, o);
  int w = threadIdx.x >> 6;
  if ((threadIdx.x & 63) == 0) s4[w] = v;
  __syncthreads();
  float r = s4[0] + s4[1] + s4[2] + s4[3];
  __syncthreads();
  return r;
}

__global__ void init_slots(float* slots) {
  if (threadIdx.x < 8) slots[threadIdx.x] = 0.0f;
}

__global__ __launch_bounds__(256) void l1_kernel(
    const float* __restrict__ igt, const float* __restrict__ iout,
    const float* __restrict__ mask, float* __restrict__ slots) {
  __shared__ float s4[4];
  float ah = 0.0f, av = 0.0f;
  for (int idx = blockIdx.x * 256 + threadIdx.x; idx < 1572864;
       idx += gridDim.x * 256) {
    int pix = idx & 262143;
    int n = idx / 786432;
    float mk = mask[n * 262144 + pix];
    bool m = (mk != 0.0f);
    float d = fabsf(iout[idx] - igt[idx]);
    if (m) av += d; else ah += d;
  }
  float r = blk_sum256(ah, s4);
  if (threadIdx.x == 0) atomicAdd(&slots[0], r);
  r = blk_sum256(av, s4);
  if (threadIdx.x == 0) atomicAdd(&slots[1], r);
}

__global__ __launch_bounds__(256) void pack_kernel(
    const float* __restrict__ igt, const float* __restrict__ iout,
    const float* __restrict__ mask, float* __restrict__ x0, int sid, int n0,
    int NB) {
  int i = blockIdx.x * 256 + threadIdx.x;
  if (i >= NB * 786432) return;
  int nl = i / 786432;
  int rem = i - nl * 786432;
  int sample = n0 + nl;
  float v;
  if (sid == 0) {
    v = igt[sample * 786432 + rem];
  } else if (sid == 1) {
    v = iout[sample * 786432 + rem];
  } else {
    int pix = rem & 262143;
    float mk = mask[sample * 262144 + pix];
    v = (mk != 0.0f) ? igt[sample * 786432 + rem] : iout[sample * 786432 + rem];
  }
  x0[i] = v;
}

// Pack fp32 OIHW weights -> bf16 [tap][cout][cin].
__global__ __launch_bounds__(256) void pack_w(const float* __restrict__ w,
                                              __hip_bfloat16* __restrict__ wp,
                                              int Cin, int Cout) {
  int i = blockIdx.x * 256 + threadIdx.x;
  if (i >= Cout * Cin * 9) return;
  int o = i % 9;
  int rem = i / 9;
  int ci = rem % Cin;
  int co = rem / Cin;
  wp[((long)(o * Cout + co)) * Cin + ci] = __float2bfloat16(w[i]);
}

// Zero the 1-px border of a padded NHWC buffer [nimg][H+2][W+2][C].
__global__ __launch_bounds__(256) void zero_border(
    __hip_bfloat16* __restrict__ buf, int nimg, int H, int W, int C) {
  const long Wp2 = W + 2;
  const long topbot = 2 * Wp2 * C;
  const long per = topbot + 2L * H * C;
  const long total = per * nimg;
  const __hip_bfloat16 z = __float2bfloat16(0.0f);
  for (long i = blockIdx.x * 256L + threadIdx.x; i < total;
       i += (long)gridDim.x * 256) {
    long n = i / per;
    long r = i - n * per;
    long cell;
    if (r < topbot) {
      long rr = r / (Wp2 * C);
      long rem = r - rr * (Wp2 * C);
      long row = rr ? (H + 1) : 0;
      cell = row * Wp2 * C + rem;
    } else {
      long r2 = r - topbot;
      long side = r2 / ((long)H * C);
      long rem = r2 - side * (long)H * C;
      long row = 1 + rem / C;
      long c = rem - (rem / C) * C;
      long col = side ? (W + 1) : 0;
      cell = (row * Wp2 + col) * C + c;
    }
    buf[n * (long)(H + 2) * Wp2 * C + cell] = z;
  }
}

// conv1: 3->64 fp32 direct, bias+relu, bf16 padded-NHWC out.
__global__ __launch_bounds__(256) void conv1_k(
    const float* __restrict__ in, const float* __restrict__ wgt,
    const float* __restrict__ bias, __hip_bfloat16* __restrict__ out,
    int H, int W) {
  constexpr int TCO = 16;
  constexpr int Cin = 3;
  __shared__ float s_in[Cin][34][34];
  __shared__ float s_w[Cin][9][TCO];
  const int tid = threadIdx.x;
  const int tx = tid & 31;
  const int tyq = tid >> 5;
  const int bx = blockIdx.x, by = blockIdx.y;
  const int n = blockIdx.z >> 2;
  const int co0 = (blockIdx.z & 3) * TCO;
  const int x0g = bx * 32 - 1;
  const int y0g = by * 32 - 1;

  float acc[4][TCO];
#pragma unroll
  for (int p = 0; p < 4; ++p)
#pragma unroll
    for (int t = 0; t < TCO; ++t) acc[p][t] = 0.0f;

  for (int e = tid; e < Cin * 1156; e += 256) {
    int ci = e / 1156;
    int rem = e - ci * 1156;
    int r = rem / 34;
    int c = rem - r * 34;
    int gy = y0g + r, gx = x0g + c;
    float v = 0.0f;
    if (gy >= 0 && gy < H && gx >= 0 && gx < W)
      v = in[((long)(n * Cin + ci) * H + gy) * W + gx];
    s_in[ci][r][c] = v;
  }
  for (int e = tid; e < Cin * 9 * TCO; e += 256) {
    int ci = e / (9 * TCO);
    int rem = e - ci * 9 * TCO;
    int k = rem / TCO;
    int t = rem - k * TCO;
    s_w[ci][k][t] = wgt[((co0 + t) * Cin + ci) * 9 + k];
  }
  __syncthreads();

  for (int ci = 0; ci < Cin; ++ci) {
    float iv[6][3];
#pragma unroll
    for (int dr = 0; dr < 6; ++dr)
#pragma unroll
      for (int dc = 0; dc < 3; ++dc)
        iv[dr][dc] = s_in[ci][tyq * 4 + dr][tx + dc];
#pragma unroll
    for (int ky = 0; ky < 3; ++ky)
#pragma unroll
      for (int kx = 0; kx < 3; ++kx) {
        const int kk = ky * 3 + kx;
        const float4 w0 = *(const float4*)&s_w[ci][kk][0];
        const float4 w1 = *(const float4*)&s_w[ci][kk][4];
        const float4 w2 = *(const float4*)&s_w[ci][kk][8];
        const float4 w3 = *(const float4*)&s_w[ci][kk][12];
        const float wv[16] = {w0.x, w0.y, w0.z, w0.w, w1.x, w1.y, w1.z, w1.w,
                              w2.x, w2.y, w2.z, w2.w, w3.x, w3.y, w3.z, w3.w};
#pragma unroll
        for (int p = 0; p < 4; ++p) {
          const float v = iv[p + ky][kx];
#pragma unroll
          for (int t = 0; t < TCO; ++t) acc[p][t] += v * wv[t];
        }
      }
  }

  float bv[TCO];
#pragma unroll
  for (int t = 0; t < TCO; ++t) bv[t] = bias[co0 + t];
  const int xg = bx * 32 + tx;
#pragma unroll
  for (int p = 0; p < 4; ++p) {
    int yg = by * 32 + tyq * 4 + p;
#pragma unroll
    for (int t = 0; t < TCO; ++t) {
      float v = fmaxf(acc[p][t] + bv[t], 0.0f);
      out[(((long)n * (H + 2) + yg + 1) * (W + 2) + xg + 1) * 64 + co0 + t] =
          __float2bfloat16(v);
    }
  }
}

// ---------------------------------------------------------------------------
// conv_v3: MFMA 3x3 conv, bias+relu, padded bf16 NHWC in/out. B from global.
// Wave = 1 row x 128 px x 64 co (m8 x n4). A-tile staged via global_load_lds
// (width 16); no bounds checks (input zero-padded). LDS 53,248 B (3 blk/CU).
// Grid: (W/128, H/4, n_imgs * Cout/64).
// ---------------------------------------------------------------------------
__global__ __launch_bounds__(256, 2) void conv_v3(
    const __hip_bfloat16* __restrict__ act,
    const __hip_bfloat16* __restrict__ wp, const float* __restrict__ bias,
    __hip_bfloat16* __restrict__ out, int Cin, int Cout, int H, int W) {
  __shared__ __align__(16) short ApS[3328 * 8];  // 3120 chunks used
  const int tid = threadIdx.x;
  const int lane = tid & 63;
  const int wv = tid >> 6;
  const int quad = lane >> 4, l15 = lane & 15;
  const int coB = Cout >> 6;
  const int n = blockIdx.z / coB;
  const int co0 = (blockIdx.z % coB) << 6;
  const int x0 = blockIdx.x << 7;
  const int y0 = blockIdx.y << 2;
  const long istr = (long)(H + 2) * (W + 2) * Cin;
  const __hip_bfloat16* actn = act + (long)n * istr;

  f32x4_t acc[8][4];
#pragma unroll
  for (int mt = 0; mt < 8; ++mt)
#pragma unroll
    for (int nt = 0; nt < 4; ++nt) acc[mt][nt] = (f32x4_t)0.0f;

  for (int cb = 0; cb < Cin; cb += 32) {
    for (int e0 = 0; e0 < 3328; e0 += 256) {
      int e = e0 + tid;
      int ec = e < 3120 ? e : 3119;
      int q = ec & 3, pos = ec >> 2;
      int r = pos / 130, c = pos - r * 130;
      const __hip_bfloat16* gp =
          actn + ((long)(y0 + r) * (W + 2) + x0 + c) * Cin + cb + q * 8;
      async16(gp, &ApS[e * 8]);
    }
    __syncthreads();

#pragma unroll
    for (int o = 0; o < 9; ++o) {
      const int dy = o / 3, dx = o % 3;
      const __hip_bfloat16* wB =
          wp + ((long)(o * Cout + co0)) * Cin + cb + quad * 8;
      bf16x8_t bf[4];
#pragma unroll
      for (int nt = 0; nt < 4; ++nt)
        bf[nt] = *(const bf16x8_t*)(wB + (long)(nt * 16 + l15) * Cin);
#pragma unroll
      for (int mt = 0; mt < 8; ++mt) {
        const bf16x8_t a = *(const bf16x8_t*)&ApS
            [((wv + dy) * 130 + mt * 16 + l15 + dx) * 32 + quad * 8];
#pragma unroll
        for (int nt = 0; nt < 4; ++nt)
          acc[mt][nt] = __builtin_amdgcn_mfma_f32_16x16x32_bf16(
              a, bf[nt], acc[mt][nt], 0, 0, 0);
      }
    }
    __syncthreads();
  }

  float bv[4];
#pragma unroll
  for (int nt = 0; nt < 4; ++nt) bv[nt] = bias[co0 + nt * 16 + l15];
  const int y = y0 + wv;
  const long ostr = (long)(H + 2) * (W + 2) * Cout;
#pragma unroll
  for (int mt = 0; mt < 8; ++mt)
#pragma unroll
    for (int nt = 0; nt < 4; ++nt) {
      const int col = co0 + nt * 16 + l15;
#pragma unroll
      for (int reg = 0; reg < 4; ++reg) {
        int px = mt * 16 + quad * 4 + reg;
        float v = fmaxf(acc[mt][nt][reg] + bv[nt], 0.0f);
        out[(long)n * ostr + ((long)(y + 1) * (W + 2) + x0 + px + 1) * Cout +
            col] = __float2bfloat16(v);
      }
    }
}

// ---------------------------------------------------------------------------
// conv_v3p: conv_v3 + fused 2x2 maxpool. Wave = 2 rows x 64 px x 64 co
// (m-tiles 0..3 row0, 4..7 row1; x-pairs = acc reg pairs; row pair mt/mt+4).
// Padded in AND padded pooled out. LDS 45,056 B. Grid: (W/64, H/8, n*Cout/64).
// ---------------------------------------------------------------------------
__global__ __launch_bounds__(256, 2) void conv_v3p(
    const __hip_bfloat16* __restrict__ act,
    const __hip_bfloat16* __restrict__ wp, const float* __restrict__ bias,
    __hip_bfloat16* __restrict__ out, int Cin, int Cout, int H, int W) {
  __shared__ __align__(16) short ApS[2816 * 8];  // 2640 chunks used
  const int tid = threadIdx.x;
  const int lane = tid & 63;
  const int wv = tid >> 6;
  const int quad = lane >> 4, l15 = lane & 15;
  const int coB = Cout >> 6;
  const int n = blockIdx.z / coB;
  const int co0 = (blockIdx.z % coB) << 6;
  const int x0g = blockIdx.x << 6;
  const int y0 = blockIdx.y << 3;
  const long istr = (long)(H + 2) * (W + 2) * Cin;
  const __hip_bfloat16* actn = act + (long)n * istr;

  f32x4_t acc[8][4];
#pragma unroll
  for (int mt = 0; mt < 8; ++mt)
#pragma unroll
    for (int nt = 0; nt < 4; ++nt) acc[mt][nt] = (f32x4_t)0.0f;

  for (int cb = 0; cb < Cin; cb += 32) {
    for (int e0 = 0; e0 < 2816; e0 += 256) {
      int e = e0 + tid;
      int ec = e < 2640 ? e : 2639;
      int q = ec & 3, pos = ec >> 2;
      int r = pos / 66, c = pos - r * 66;
      const __hip_bfloat16* gp =
          actn + ((long)(y0 + r) * (W + 2) + x0g + c) * Cin + cb + q * 8;
      async16(gp, &ApS[e * 8]);
    }
    __syncthreads();

#pragma unroll
    for (int o = 0; o < 9; ++o) {
      const int dy = o / 3, dx = o % 3;
      const __hip_bfloat16* wB =
          wp + ((long)(o * Cout + co0)) * Cin + cb + quad * 8;
      bf16x8_t bf[4];
#pragma unroll
      for (int nt = 0; nt < 4; ++nt)
        bf[nt] = *(const bf16x8_t*)(wB + (long)(nt * 16 + l15) * Cin);
#pragma unroll
      for (int mt = 0; mt < 8; ++mt) {
        const int rl = 2 * wv + (mt >> 2) + dy;
        const int pl = (mt & 3) * 16 + l15 + dx;
        const bf16x8_t a =
            *(const bf16x8_t*)&ApS[(rl * 66 + pl) * 32 + quad * 8];
#pragma unroll
        for (int nt = 0; nt < 4; ++nt)
          acc[mt][nt] = __builtin_amdgcn_mfma_f32_16x16x32_bf16(
              a, bf[nt], acc[mt][nt], 0, 0, 0);
      }
    }
    __syncthreads();
  }

  const int Ho = H >> 1, Wo = W >> 1;
  const int ho = (blockIdx.y << 2) + wv;
  const long ostr = (long)(Ho + 2) * (Wo + 2) * Cout;
  float bv[4];
#pragma unroll
  for (int nt = 0; nt < 4; ++nt) bv[nt] = bias[co0 + nt * 16 + l15];
#pragma unroll
  for (int mtA = 0; mtA < 4; ++mtA)
#pragma unroll
    for (int nt = 0; nt < 4; ++nt) {
      const int col = co0 + nt * 16 + l15;
#pragma unroll
      for (int half = 0; half < 2; ++half) {
        float m0 = fmaxf(
            fmaxf(acc[mtA][nt][2 * half], acc[mtA][nt][2 * half + 1]),
            fmaxf(acc[mtA + 4][nt][2 * half], acc[mtA + 4][nt][2 * half + 1]));
        float v = fmaxf(m0 + bv[nt], 0.0f);
        int wo = (blockIdx.x << 5) + mtA * 8 + quad * 2 + half;
        out[(long)n * ostr + ((long)(ho + 1) * (Wo + 2) + wo + 1) * Cout +
            col] = __float2bfloat16(v);
      }
    }
}

// Padded NHWC [j][Ho+2][Wo+2][C] -> col-major planar [(j*C+c)][Wo][Ho].
__global__ __launch_bounds__(256) void transpose_k(
    const __hip_bfloat16* __restrict__ in, __hip_bfloat16* __restrict__ out,
    int C, int Ho, int Wo) {
  const int cl = threadIdx.x & 31;
  const int wl = threadIdx.x >> 5;
  const int cg = C >> 5;
  const int j = blockIdx.z / cg;
  const int c = (blockIdx.z % cg) * 32 + cl;
  const int wo = blockIdx.x * 8 + wl;
  const int ho0 = blockIdx.y * 8;
  const long istr = (long)(Ho + 2) * (Wo + 2) * C;
  __align__(16) __hip_bfloat16 res[8];
#pragma unroll
  for (int i = 0; i < 8; ++i)
    res[i] = in[(long)j * istr + ((long)(ho0 + i + 1) * (Wo + 2) + wo + 1) * C +
                c];
  *(uint4*)&out[((long)(j * C + c) * Wo + wo) * Ho + ho0] =
      *(const uint4*)res;
}

// l_perc partial: sum |cur - gt| over 8*M8 bf16 elements -> slots[2]
__global__ __launch_bounds__(256) void perc_kernel(
    const __hip_bfloat16* __restrict__ gt, const __hip_bfloat16* __restrict__ cur,
    int M8, float* __restrict__ slots) {
  __shared__ float s4[4];
  const uint4* g4 = (const uint4*)gt;
  const uint4* c4 = (const uint4*)cur;
  float acc = 0.0f;
  for (int i = blockIdx.x * 256 + threadIdx.x; i < M8; i += gridDim.x * 256) {
    uint4 g = g4[i], c = c4[i];
    const unsigned* gu = (const unsigned*)&g;
    const unsigned* cu = (const unsigned*)&c;
#pragma unroll
    for (int k = 0; k < 4; ++k) {
      float g0 = __uint_as_float(gu[k] << 16);
      float g1 = __uint_as_float(gu[k] & 0xffff0000u);
      float c0 = __uint_as_float(cu[k] << 16);
      float c1 = __uint_as_float(cu[k] & 0xffff0000u);
      acc += fabsf(c0 - g0) + fabsf(c1 - g1);
    }
  }
  float r = blk_sum256(acc, s4);
  if (threadIdx.x == 0) atomicAdd(&slots[2], r);
}

// Style partial via bf16 MFMA (r5-proven). Inputs col-major planar bf16.
template <int BM>
__global__ __launch_bounds__(256) void gram_mfma(
    const __hip_bfloat16* __restrict__ gt_p,
    const __hip_bfloat16* __restrict__ cur_p, int Wp, int Hp, float fscale,
    float* __restrict__ slots) {
  constexpr int COLS = BM + 64;
  constexpr int WR = BM / 4;
  constexpr int MT = WR / 16;
  __shared__ __align__(16) short S[2 * COLS * 40];
  __shared__ float s4[4];
  const int tid = threadIdx.x;
  const int lane = tid & 63;
  const int wvi = tid >> 6;
  const int quad = lane >> 4, l15 = lane & 15;
  const int vt = blockIdx.x * 64;
  const int wt = blockIdx.y * BM;
  const long plane = (long)blockIdx.z * Wp * Hp;
  const __hip_bfloat16* bases[2] = {gt_p + plane, cur_p + plane};

  f32x4_t acc[2][MT][4];
#pragma unroll
  for (int t = 0; t < 2; ++t)
#pragma unroll
    for (int mt = 0; mt < MT; ++mt)
#pragma unroll
      for (int nt = 0; nt < 4; ++nt) acc[t][mt][nt] = (f32x4_t)0.0f;

  const int nchunk = 2 * COLS * 4;
  for (int h0 = 0; h0 < Hp; h0 += 32) {
    for (int e = tid; e < nchunk; e += 256) {
      int chunk = e & 3;
      int colt = e >> 2;
      int t = colt / COLS;
      int col = colt - t * COLS;
      int sc = (col < BM) ? (wt + col) : (vt + col - BM);
      uint4 v = *(const uint4*)(bases[t] + (long)sc * Hp + h0 + chunk * 8);
      *(uint4*)&S[(t * COLS + col) * 40 + chunk * 8] = v;
    }
    __syncthreads();
#pragma unroll
    for (int t = 0; t < 2; ++t) {
      bf16x8_t bf[4];
#pragma unroll
      for (int nt = 0; nt < 4; ++nt)
        bf[nt] = *(const bf16x8_t*)&S[(t * COLS + BM + nt * 16 + l15) * 40 +
                                      quad * 8];
#pragma unroll
      for (int mt = 0; mt < MT; ++mt) {
        bf16x8_t a = *(const bf16x8_t*)&S[(t * COLS + wvi * WR + mt * 16 + l15) *
                                              40 + quad * 8];
#pragma unroll
        for (int nt = 0; nt < 4; ++nt)
          acc[t][mt][nt] = __builtin_amdgcn_mfma_f32_16x16x32_bf16(
              a, bf[nt], acc[t][mt][nt], 0, 0, 0);
      }
    }
    __syncthreads();
  }

  float local = 0.0f;
#pragma unroll
  for (int mt = 0; mt < MT; ++mt)
#pragma unroll
    for (int nt = 0; nt < 4; ++nt)
#pragma unroll
      for (int reg = 0; reg < 4; ++reg)
        local += fabsf(acc[1][mt][nt][reg] - acc[0][mt][nt][reg]);
  float r = blk_sum256(local, s4);
  if (tid == 0) atomicAdd(&slots[3], r * fscale);
}

__global__ void combine_kernel(const float* __restrict__ slots,
                               float* __restrict__ out) {
  if (threadIdx.x == 0) {
    const float Nn = 1572864.0f;
    const float Nigt = 8388608.0f;
    out[0] = 2.0f * slots[0] / Nn + slots[1] / Nn + slots[2] / Nigt + slots[3];
  }
}

extern "C" void kernel_launch(void* const* d_in, const int* in_sizes, int n_in,
                              void* d_out, int out_size, void* d_ws,
                              size_t ws_size, hipStream_t stream) {
  (void)in_sizes; (void)n_in; (void)out_size;
  const float* igt = (const float*)d_in[0];
  const float* iout = (const float*)d_in[1];
  const float* mask = (const float*)d_in[2];
  const float* w[7];
  const float* b[7];
  for (int i = 0; i < 7; ++i) {
    w[i] = (const float*)d_in[3 + 2 * i];
    b[i] = (const float*)d_in[4 + 2 * i];
  }
  float* slots = (float*)d_ws;

  __hip_bfloat16* wpk = (__hip_bfloat16*)((char*)d_ws + 256);
  const long wpOff[6] = {0, 36864, 110592, 258048, 552960, 1142784};
  const int wpCin[6] = {64, 64, 128, 128, 256, 256};
  const int wpCout[6] = {64, 128, 128, 256, 256, 256};
  // weights end at byte 3,465,472

  // NB=2 tier: 3,465,472 + 2*97,400,320 = 198,266,112 B; NB=1: 100.9MB.
  const size_t NEED2 = 198266112ULL;
  const int NB = (ws_size >= NEED2) ? 2 : 1;
  const int B3 = 3 * NB;

  char* base = (char*)d_ws + 3465472;
  // Phase-F layout (byte offsets * NB):
  __hip_bfloat16* P1N = (__hip_bfloat16*)base;                          // 3NB*8,520,192
  __hip_bfloat16* pgT1 = (__hip_bfloat16*)(base + (size_t)NB * 25560576);
  __hip_bfloat16* pcT1 = (__hip_bfloat16*)(base + (size_t)NB * 33949184);
  float* x0 = (float*)(base + (size_t)NB * 42337792);
  __hip_bfloat16* Y1 = (__hip_bfloat16*)(base + (size_t)NB * 45483520);
  // Phase-M aliases (live ranges strictly sequential):
  __hip_bfloat16* T = (__hip_bfloat16*)(base + (size_t)NB * 45483520);   // over Y1
  __hip_bfloat16* P2N = (__hip_bfloat16*)(base + (size_t)NB * 25560576); // over pgT1/pcT1
  __hip_bfloat16* P2T = (__hip_bfloat16*)base;                           // over P1N
  __hip_bfloat16* Y5 = (__hip_bfloat16*)(base + (size_t)NB * 45483520);  // over T
  __hip_bfloat16* Y6 = (__hip_bfloat16*)(base + (size_t)NB * 71441920);
  __hip_bfloat16* P3N = (__hip_bfloat16*)(base + (size_t)NB * 12582912);
  __hip_bfloat16* P3T = (__hip_bfloat16*)(base + (size_t)NB * 19273728);

  const float fs1 = (float)(1.0 / (4194304.0 * 4096.0));
  const float fs2 = (float)(1.0 / (2097152.0 * 16384.0));
  const float fs3 = (float)(1.0 / (1048576.0 * 65536.0));

  init_slots<<<1, 64, 0, stream>>>(slots);
  l1_kernel<<<304, 256, 0, stream>>>(igt, iout, mask, slots);
  for (int l = 0; l < 6; ++l) {
    int elems = wpCout[l] * wpCin[l] * 9;
    pack_w<<<(elems + 255) / 256, 256, 0, stream>>>(w[l + 1], wpk + wpOff[l],
                                                    wpCin[l], wpCout[l]);
  }

  for (int n0 = 0; n0 < 2; n0 += NB) {
    zero_border<<<512, 256, 0, stream>>>(Y1, NB, 512, 512, 64);
    zero_border<<<512, 256, 0, stream>>>(P1N, B3, 256, 256, 64);
    // ---- per-stream front end: conv1, conv2+pool, gram1/perc1 ----
    for (int s = 0; s < 3; ++s) {
      __hip_bfloat16* slot = P1N + (size_t)s * NB * 4260096;
      pack_kernel<<<NB * 3072, 256, 0, stream>>>(igt, iout, mask, x0, s, n0, NB);
      conv1_k<<<dim3(16, 16, NB * 4), 256, 0, stream>>>(x0, w[0], b[0], Y1, 512, 512);
      conv_v3p<<<dim3(8, 64, NB), 256, 0, stream>>>(
          Y1, wpk + wpOff[0], b[1], slot, 64, 64, 512, 512);
      transpose_k<<<dim3(32, 32, NB * 2), 256, 0, stream>>>(
          slot, (s ? pcT1 : pgT1), 64, 256, 256);
      if (s > 0) {
        perc_kernel<<<304, 256, 0, stream>>>(pgT1, pcT1, NB * 524288, slots);
        gram_mfma<128><<<dim3(4, 2, NB * 64), 256, 0, stream>>>(
            pgT1, pcT1, 256, 256, fs1, slots);
      }
    }
    // ---- batched over 3NB images: conv3..conv7 ----
    zero_border<<<512, 256, 0, stream>>>(T, B3, 256, 256, 128);
    conv_v3<<<dim3(2, 64, B3 * 2), 256, 0, stream>>>(
        P1N, wpk + wpOff[1], b[2], T, 64, 128, 256, 256);
    zero_border<<<512, 256, 0, stream>>>(P2N, B3, 128, 128, 128);
    conv_v3p<<<dim3(4, 32, B3 * 2), 256, 0, stream>>>(
        T, wpk + wpOff[2], b[3], P2N, 128, 128, 256, 256);
    transpose_k<<<dim3(16, 16, B3 * 4), 256, 0, stream>>>(P2N, P2T, 128, 128, 128);
    for (int s = 1; s <= 2; ++s) {
      perc_kernel<<<304, 256, 0, stream>>>(
          P2T, P2T + (size_t)s * NB * 2097152, NB * 262144, slots);
      gram_mfma<128><<<dim3(2, 1, NB * 128), 256, 0, stream>>>(
          P2T, P2T + (size_t)s * NB * 2097152, 128, 128, fs2, slots);
    }
    zero_border<<<512, 256, 0, stream>>>(Y5, B3, 128, 128, 256);
    conv_v3<<<dim3(1, 32, B3 * 4), 256, 0, stream>>>(
        P2N, wpk + wpOff[3], b[4], Y5, 128, 256, 128, 128);
    zero_border<<<512, 256, 0, stream>>>(Y6, B3, 128, 128, 256);
    conv_v3<<<dim3(1, 32, B3 * 4), 256, 0, stream>>>(
        Y5, wpk + wpOff[4], b[5], Y6, 256, 256, 128, 128);
    conv_v3p<<<dim3(2, 16, B3 * 4), 256, 0, stream>>>(
        Y6, wpk + wpOff[5], b[6], P3N, 256, 256, 128, 128);
    transpose_k<<<dim3(8, 8, B3 * 8), 256, 0, stream>>>(P3N, P3T, 256, 64, 64);
    for (int s = 1; s <= 2; ++s) {
      perc_kernel<<<304, 256, 0, stream>>>(
          P3T, P3T + (size_t)s * NB * 1048576, NB * 131072, slots);
      gram_mfma<64><<<dim3(1, 1, NB * 256), 256, 0, stream>>>(
          P3T, P3T + (size_t)s * NB * 1048576, 64, 64, fs3, slots);
    }
  }

  combine_kernel<<<1, 64, 0, stream>>>(slots, (float*)d_out);
}

// Round 9
// 1279.839 us; speedup vs baseline: 1.4275x; 1.4275x over previous
//
#include <hip/hip_runtime.h>
#include <hip/hip_bf16.h>

// ---------------------------------------------------------------------------
// VGG16 perceptual+style inpainting loss.
// conv2..7: bf16 MFMA NHWC. v4: A-tile AND W-tile in LDS (no VMEM in the
// MFMA loop — r8 showed in-loop global weight loads miss L2 under streaming).
// Wave = 2 rows x 64 px x 64 co (m8n4). LDS 79,104B -> 2 blocks/CU.
// conv4/conv7 fuse 2x2 maxpool in-register. conv3..7 batched over 3 streams.
// conv1 fp32-direct. Gram: bf16 MFMA planar. l1/perc grid-stride.
// Workspace: identical to r7 (NB=2 needs 211.1MB, NB=1 107.3MB).
// ---------------------------------------------------------------------------

typedef __attribute__((ext_vector_type(8))) short bf16x8_t;
typedef __attribute__((ext_vector_type(4))) float f32x4_t;

__device__ __forceinline__ float b2f(__hip_bfloat16 v) {
  return __bfloat162float(v);
}

__device__ __forceinline__ float blk_sum256(float v, float* s4) {
#pragma unroll
  for (int o = 32; o > 0; o >>= 1) v += __shfl_down(v, o);
  int w = threadIdx.x >> 6;
  if ((threadIdx.x & 63) == 0) s4[w] = v;
  __syncthreads();
  float r = s4[0] + s4[1] + s4[2] + s4[3];
  __syncthreads();
  return r;
}

__global__ void init_slots(float* slots) {
  if (threadIdx.x < 8) slots[threadIdx.x] = 0.0f;
}

__global__ __launch_bounds__(256) void l1_kernel(
    const float* __restrict__ igt, const float* __restrict__ iout,
    const float* __restrict__ mask, float* __restrict__ slots) {
  __shared__ float s4[4];
  float ah = 0.0f, av = 0.0f;
  for (int idx = blockIdx.x * 256 + threadIdx.x; idx < 1572864;
       idx += gridDim.x * 256) {
    int pix = idx & 262143;
    int n = idx / 786432;
    float mk = mask[n * 262144 + pix];
    bool m = (mk != 0.0f);
    float d = fabsf(iout[idx] - igt[idx]);
    if (m) av += d; else ah += d;
  }
  float r = blk_sum256(ah, s4);
  if (threadIdx.x == 0) atomicAdd(&slots[0], r);
  r = blk_sum256(av, s4);
  if (threadIdx.x == 0) atomicAdd(&slots[1], r);
}

__global__ __launch_bounds__(256) void pack_kernel(
    const float* __restrict__ igt, const float* __restrict__ iout,
    const float* __restrict__ mask, float* __restrict__ x0, int sid, int n0,
    int NB) {
  int i = blockIdx.x * 256 + threadIdx.x;
  if (i >= NB * 786432) return;
  int nl = i / 786432;
  int rem = i - nl * 786432;
  int sample = n0 + nl;
  float v;
  if (sid == 0) {
    v = igt[sample * 786432 + rem];
  } else if (sid == 1) {
    v = iout[sample * 786432 + rem];
  } else {
    int pix = rem & 262143;
    float mk = mask[sample * 262144 + pix];
    v = (mk != 0.0f) ? igt[sample * 786432 + rem] : iout[sample * 786432 + rem];
  }
  x0[i] = v;
}

// Pack fp32 OIHW weights -> bf16 [tap][cout][cin].
__global__ __launch_bounds__(256) void pack_w(const float* __restrict__ w,
                                              __hip_bfloat16* __restrict__ wp,
                                              int Cin, int Cout) {
  int i = blockIdx.x * 256 + threadIdx.x;
  if (i >= Cout * Cin * 9) return;
  int o = i % 9;
  int rem = i / 9;
  int ci = rem % Cin;
  int co = rem / Cin;
  wp[((long)(o * Cout + co)) * Cin + ci] = __float2bfloat16(w[i]);
}

// conv1: 3->64 fp32 direct, bias+relu, bf16 NHWC out. (r4-proven)
__global__ __launch_bounds__(256) void conv1_k(
    const float* __restrict__ in, const float* __restrict__ wgt,
    const float* __restrict__ bias, __hip_bfloat16* __restrict__ out,
    int H, int W) {
  constexpr int TCO = 16;
  constexpr int Cin = 3;
  __shared__ float s_in[Cin][34][34];
  __shared__ float s_w[Cin][9][TCO];
  const int tid = threadIdx.x;
  const int tx = tid & 31;
  const int tyq = tid >> 5;
  const int bx = blockIdx.x, by = blockIdx.y;
  const int n = blockIdx.z >> 2;
  const int co0 = (blockIdx.z & 3) * TCO;
  const int x0g = bx * 32 - 1;
  const int y0g = by * 32 - 1;

  float acc[4][TCO];
#pragma unroll
  for (int p = 0; p < 4; ++p)
#pragma unroll
    for (int t = 0; t < TCO; ++t) acc[p][t] = 0.0f;

  for (int e = tid; e < Cin * 1156; e += 256) {
    int ci = e / 1156;
    int rem = e - ci * 1156;
    int r = rem / 34;
    int c = rem - r * 34;
    int gy = y0g + r, gx = x0g + c;
    float v = 0.0f;
    if (gy >= 0 && gy < H && gx >= 0 && gx < W)
      v = in[((long)(n * Cin + ci) * H + gy) * W + gx];
    s_in[ci][r][c] = v;
  }
  for (int e = tid; e < Cin * 9 * TCO; e += 256) {
    int ci = e / (9 * TCO);
    int rem = e - ci * 9 * TCO;
    int k = rem / TCO;
    int t = rem - k * TCO;
    s_w[ci][k][t] = wgt[((co0 + t) * Cin + ci) * 9 + k];
  }
  __syncthreads();

  for (int ci = 0; ci < Cin; ++ci) {
    float iv[6][3];
#pragma unroll
    for (int dr = 0; dr < 6; ++dr)
#pragma unroll
      for (int dc = 0; dc < 3; ++dc)
        iv[dr][dc] = s_in[ci][tyq * 4 + dr][tx + dc];
#pragma unroll
    for (int ky = 0; ky < 3; ++ky)
#pragma unroll
      for (int kx = 0; kx < 3; ++kx) {
        const int kk = ky * 3 + kx;
        const float4 w0 = *(const float4*)&s_w[ci][kk][0];
        const float4 w1 = *(const float4*)&s_w[ci][kk][4];
        const float4 w2 = *(const float4*)&s_w[ci][kk][8];
        const float4 w3 = *(const float4*)&s_w[ci][kk][12];
        const float wv[16] = {w0.x, w0.y, w0.z, w0.w, w1.x, w1.y, w1.z, w1.w,
                              w2.x, w2.y, w2.z, w2.w, w3.x, w3.y, w3.z, w3.w};
#pragma unroll
        for (int p = 0; p < 4; ++p) {
          const float v = iv[p + ky][kx];
#pragma unroll
          for (int t = 0; t < TCO; ++t) acc[p][t] += v * wv[t];
        }
      }
  }

  float bv[TCO];
#pragma unroll
  for (int t = 0; t < TCO; ++t) bv[t] = bias[co0 + t];
  const int xg = bx * 32 + tx;
#pragma unroll
  for (int p = 0; p < 4; ++p) {
    int yg = by * 32 + tyq * 4 + p;
#pragma unroll
    for (int t = 0; t < TCO; ++t) {
      float v = fmaxf(acc[p][t] + bv[t], 0.0f);
      out[(((long)n * H + yg) * W + xg) * 64 + co0 + t] = __float2bfloat16(v);
    }
  }
}

// ---------------------------------------------------------------------------
// conv_v4: MFMA 3x3 conv, bias+relu, bf16 NHWC. A-tile + W-tile in LDS.
// Block 256 = 4 waves; wave = 2 rows x 64 px x 64 co (m8n4: mt0..3 row 2wv,
// mt4..7 row 2wv+1). A: 10x66x32ch = 42,240B; W: 9x64x32 = 36,864B.
// Grid: (W/64, H/8, n_imgs * Cout/64). 2 blocks/CU.
// ---------------------------------------------------------------------------
__global__ __launch_bounds__(256, 2) void conv_v4(
    const __hip_bfloat16* __restrict__ act,
    const __hip_bfloat16* __restrict__ wp, const float* __restrict__ bias,
    __hip_bfloat16* __restrict__ out, int Cin, int Cout, int H, int W) {
  __shared__ __align__(16) short ApS[2640 * 8];
  __shared__ __align__(16) short BwS[2304 * 8];
  const int tid = threadIdx.x;
  const int lane = tid & 63;
  const int wv = tid >> 6;
  const int quad = lane >> 4, l15 = lane & 15;
  const int coB = Cout >> 6;
  const int n = blockIdx.z / coB;
  const int co0 = (blockIdx.z % coB) << 6;
  const int x0 = blockIdx.x << 6;
  const int y0 = blockIdx.y << 3;

  f32x4_t acc[8][4];
#pragma unroll
  for (int mt = 0; mt < 8; ++mt)
#pragma unroll
    for (int nt = 0; nt < 4; ++nt) acc[mt][nt] = (f32x4_t)0.0f;

  for (int cb = 0; cb < Cin; cb += 32) {
    for (int e = tid; e < 2640; e += 256) {  // A: 10*66 px * 4 chunks
      int q = e & 3, pos = e >> 2;
      int r = pos / 66, c = pos - r * 66;
      int gy = y0 - 1 + r, gx = x0 - 1 + c;
      uint4 v = make_uint4(0, 0, 0, 0);
      if (gy >= 0 && gy < H && gx >= 0 && gx < W)
        v = *(const uint4*)(act + (((long)n * H + gy) * W + gx) * Cin + cb +
                            q * 8);
      *(uint4*)&ApS[pos * 32 + q * 8] = v;
    }
    for (int e = tid; e < 2304; e += 256) {  // W: 9*64 * 4 chunks
      int q = e & 3, idx = e >> 2;
      int o = idx >> 6, co = idx & 63;
      *(uint4*)&BwS[idx * 32 + q * 8] =
          *(const uint4*)(wp + ((long)(o * Cout + co0 + co)) * Cin + cb +
                          q * 8);
    }
    __syncthreads();

#pragma unroll
    for (int o = 0; o < 9; ++o) {
      const int dy = o / 3, dx = o % 3;
      bf16x8_t bf[4];
#pragma unroll
      for (int nt = 0; nt < 4; ++nt)
        bf[nt] = *(const bf16x8_t*)&BwS[((o << 6) + nt * 16 + l15) * 32 +
                                        quad * 8];
#pragma unroll
      for (int mt = 0; mt < 8; ++mt) {
        const int rl = 2 * wv + (mt >> 2) + dy;   // 0..9
        const int pl = (mt & 3) * 16 + l15 + dx;  // 0..65
        const bf16x8_t a =
            *(const bf16x8_t*)&ApS[(rl * 66 + pl) * 32 + quad * 8];
#pragma unroll
        for (int nt = 0; nt < 4; ++nt)
          acc[mt][nt] = __builtin_amdgcn_mfma_f32_16x16x32_bf16(
              a, bf[nt], acc[mt][nt], 0, 0, 0);
      }
    }
    __syncthreads();
  }

  float bv[4];
#pragma unroll
  for (int nt = 0; nt < 4; ++nt) bv[nt] = bias[co0 + nt * 16 + l15];
#pragma unroll
  for (int mt = 0; mt < 8; ++mt) {
    const int y = y0 + 2 * wv + (mt >> 2);
#pragma unroll
    for (int nt = 0; nt < 4; ++nt) {
      const int col = co0 + nt * 16 + l15;
#pragma unroll
      for (int reg = 0; reg < 4; ++reg) {
        int px = (mt & 3) * 16 + quad * 4 + reg;
        float v = fmaxf(acc[mt][nt][reg] + bv[nt], 0.0f);
        out[(((long)n * H + y) * W + x0 + px) * Cout + col] =
            __float2bfloat16(v);
      }
    }
  }
}

// ---------------------------------------------------------------------------
// conv_v4p: conv_v4 + fused 2x2 maxpool (x-pairs = acc reg pairs; row pair
// mt vs mt+4). Output pooled bf16 NHWC. Same LDS/grid as conv_v4.
// ---------------------------------------------------------------------------
__global__ __launch_bounds__(256, 2) void conv_v4p(
    const __hip_bfloat16* __restrict__ act,
    const __hip_bfloat16* __restrict__ wp, const float* __restrict__ bias,
    __hip_bfloat16* __restrict__ out, int Cin, int Cout, int H, int W) {
  __shared__ __align__(16) short ApS[2640 * 8];
  __shared__ __align__(16) short BwS[2304 * 8];
  const int tid = threadIdx.x;
  const int lane = tid & 63;
  const int wv = tid >> 6;
  const int quad = lane >> 4, l15 = lane & 15;
  const int coB = Cout >> 6;
  const int n = blockIdx.z / coB;
  const int co0 = (blockIdx.z % coB) << 6;
  const int x0g = blockIdx.x << 6;
  const int y0 = blockIdx.y << 3;

  f32x4_t acc[8][4];
#pragma unroll
  for (int mt = 0; mt < 8; ++mt)
#pragma unroll
    for (int nt = 0; nt < 4; ++nt) acc[mt][nt] = (f32x4_t)0.0f;

  for (int cb = 0; cb < Cin; cb += 32) {
    for (int e = tid; e < 2640; e += 256) {
      int q = e & 3, pos = e >> 2;
      int r = pos / 66, c = pos - r * 66;
      int gy = y0 - 1 + r, gx = x0g - 1 + c;
      uint4 v = make_uint4(0, 0, 0, 0);
      if (gy >= 0 && gy < H && gx >= 0 && gx < W)
        v = *(const uint4*)(act + (((long)n * H + gy) * W + gx) * Cin + cb +
                            q * 8);
      *(uint4*)&ApS[pos * 32 + q * 8] = v;
    }
    for (int e = tid; e < 2304; e += 256) {
      int q = e & 3, idx = e >> 2;
      int o = idx >> 6, co = idx & 63;
      *(uint4*)&BwS[idx * 32 + q * 8] =
          *(const uint4*)(wp + ((long)(o * Cout + co0 + co)) * Cin + cb +
                          q * 8);
    }
    __syncthreads();

#pragma unroll
    for (int o = 0; o < 9; ++o) {
      const int dy = o / 3, dx = o % 3;
      bf16x8_t bf[4];
#pragma unroll
      for (int nt = 0; nt < 4; ++nt)
        bf[nt] = *(const bf16x8_t*)&BwS[((o << 6) + nt * 16 + l15) * 32 +
                                        quad * 8];
#pragma unroll
      for (int mt = 0; mt < 8; ++mt) {
        const int rl = 2 * wv + (mt >> 2) + dy;
        const int pl = (mt & 3) * 16 + l15 + dx;
        const bf16x8_t a =
            *(const bf16x8_t*)&ApS[(rl * 66 + pl) * 32 + quad * 8];
#pragma unroll
        for (int nt = 0; nt < 4; ++nt)
          acc[mt][nt] = __builtin_amdgcn_mfma_f32_16x16x32_bf16(
              a, bf[nt], acc[mt][nt], 0, 0, 0);
      }
    }
    __syncthreads();
  }

  const int Ho = H >> 1, Wo = W >> 1;
  const int ho = (blockIdx.y << 2) + wv;
  float bv[4];
#pragma unroll
  for (int nt = 0; nt < 4; ++nt) bv[nt] = bias[co0 + nt * 16 + l15];
#pragma unroll
  for (int mtA = 0; mtA < 4; ++mtA)
#pragma unroll
    for (int nt = 0; nt < 4; ++nt) {
      const int col = co0 + nt * 16 + l15;
#pragma unroll
      for (int half = 0; half < 2; ++half) {
        float m0 = fmaxf(
            fmaxf(acc[mtA][nt][2 * half], acc[mtA][nt][2 * half + 1]),
            fmaxf(acc[mtA + 4][nt][2 * half], acc[mtA + 4][nt][2 * half + 1]));
        float v = fmaxf(m0 + bv[nt], 0.0f);
        int wo = (blockIdx.x << 5) + mtA * 8 + quad * 2 + half;
        out[(((long)n * Ho + ho) * Wo + wo) * Cout + col] = __float2bfloat16(v);
      }
    }
}

// 2x2 maxpool: bf16 NHWC in -> bf16 NHWC out + bf16 col-major planar
// out_pT[plane][x][y]. (r5-proven; L1 level only.)
__global__ __launch_bounds__(256) void pool_k(
    const __hip_bfloat16* __restrict__ in, __hip_bfloat16* __restrict__ out_n,
    __hip_bfloat16* __restrict__ out_pT, int C, int H, int W) {
  const int Ho = H >> 1, Wo = W >> 1;
  const int cl = threadIdx.x & 31;
  const int wl = threadIdx.x >> 5;
  const int cg = C >> 5;
  const int nl = blockIdx.z / cg;
  const int c = (blockIdx.z % cg) * 32 + cl;
  const int wo = blockIdx.x * 8 + wl;
  const int ho0 = blockIdx.y * 8;
  __align__(16) __hip_bfloat16 res[8];
#pragma unroll
  for (int i = 0; i < 8; ++i) {
    int ho = ho0 + i;
    long base = (((long)nl * H + 2 * ho) * W + 2 * wo) * C + c;
    float a = b2f(in[base]);
    float b = b2f(in[base + C]);
    float d = b2f(in[base + (long)W * C]);
    float e = b2f(in[base + (long)W * C + C]);
    float m = fmaxf(fmaxf(a, b), fmaxf(d, e));
    __hip_bfloat16 r = __float2bfloat16(m);
    res[i] = r;
    out_n[(((long)nl * Ho + ho) * Wo + wo) * C + c] = r;
  }
  *(uint4*)&out_pT[((long)(nl * C + c) * Wo + wo) * Ho + ho0] =
      *(const uint4*)res;
}

// NHWC [j][Ho][Wo][C] -> col-major planar [(j*C+c)][Wo][Ho].
__global__ __launch_bounds__(256) void transpose_k(
    const __hip_bfloat16* __restrict__ in, __hip_bfloat16* __restrict__ out,
    int C, int Ho, int Wo) {
  const int cl = threadIdx.x & 31;
  const int wl = threadIdx.x >> 5;
  const int cg = C >> 5;
  const int j = blockIdx.z / cg;
  const int c = (blockIdx.z % cg) * 32 + cl;
  const int wo = blockIdx.x * 8 + wl;
  const int ho0 = blockIdx.y * 8;
  __align__(16) __hip_bfloat16 res[8];
#pragma unroll
  for (int i = 0; i < 8; ++i)
    res[i] = in[(((long)j * Ho + ho0 + i) * Wo + wo) * C + c];
  *(uint4*)&out[((long)(j * C + c) * Wo + wo) * Ho + ho0] =
      *(const uint4*)res;
}

// l_perc partial: sum |cur - gt| over 8*M8 bf16 elements -> slots[2]
__global__ __launch_bounds__(256) void perc_kernel(
    const __hip_bfloat16* __restrict__ gt, const __hip_bfloat16* __restrict__ cur,
    int M8, float* __restrict__ slots) {
  __shared__ float s4[4];
  const uint4* g4 = (const uint4*)gt;
  const uint4* c4 = (const uint4*)cur;
  float acc = 0.0f;
  for (int i = blockIdx.x * 256 + threadIdx.x; i < M8; i += gridDim.x * 256) {
    uint4 g = g4[i], c = c4[i];
    const unsigned* gu = (const unsigned*)&g;
    const unsigned* cu = (const unsigned*)&c;
#pragma unroll
    for (int k = 0; k < 4; ++k) {
      float g0 = __uint_as_float(gu[k] << 16);
      float g1 = __uint_as_float(gu[k] & 0xffff0000u);
      float c0 = __uint_as_float(cu[k] << 16);
      float c1 = __uint_as_float(cu[k] & 0xffff0000u);
      acc += fabsf(c0 - g0) + fabsf(c1 - g1);
    }
  }
  float r = blk_sum256(acc, s4);
  if (threadIdx.x == 0) atomicAdd(&slots[2], r);
}

// Style partial via bf16 MFMA (r5-proven). Inputs col-major planar bf16.
template <int BM>
__global__ __launch_bounds__(256) void gram_mfma(
    const __hip_bfloat16* __restrict__ gt_p,
    const __hip_bfloat16* __restrict__ cur_p, int Wp, int Hp, float fscale,
    float* __restrict__ slots) {
  constexpr int COLS = BM + 64;
  constexpr int WR = BM / 4;
  constexpr int MT = WR / 16;
  __shared__ __align__(16) short S[2 * COLS * 40];
  __shared__ float s4[4];
  const int tid = threadIdx.x;
  const int lane = tid & 63;
  const int wvi = tid >> 6;
  const int quad = lane >> 4, l15 = lane & 15;
  const int vt = blockIdx.x * 64;
  const int wt = blockIdx.y * BM;
  const long plane = (long)blockIdx.z * Wp * Hp;
  const __hip_bfloat16* bases[2] = {gt_p + plane, cur_p + plane};

  f32x4_t acc[2][MT][4];
#pragma unroll
  for (int t = 0; t < 2; ++t)
#pragma unroll
    for (int mt = 0; mt < MT; ++mt)
#pragma unroll
      for (int nt = 0; nt < 4; ++nt) acc[t][mt][nt] = (f32x4_t)0.0f;

  const int nchunk = 2 * COLS * 4;
  for (int h0 = 0; h0 < Hp; h0 += 32) {
    for (int e = tid; e < nchunk; e += 256) {
      int chunk = e & 3;
      int colt = e >> 2;
      int t = colt / COLS;
      int col = colt - t * COLS;
      int sc = (col < BM) ? (wt + col) : (vt + col - BM);
      uint4 v = *(const uint4*)(bases[t] + (long)sc * Hp + h0 + chunk * 8);
      *(uint4*)&S[(t * COLS + col) * 40 + chunk * 8] = v;
    }
    __syncthreads();
#pragma unroll
    for (int t = 0; t < 2; ++t) {
      bf16x8_t bf[4];
#pragma unroll
      for (int nt = 0; nt < 4; ++nt)
        bf[nt] = *(const bf16x8_t*)&S[(t * COLS + BM + nt * 16 + l15) * 40 +
                                      quad * 8];
#pragma unroll
      for (int mt = 0; mt < MT; ++mt) {
        bf16x8_t a = *(const bf16x8_t*)&S[(t * COLS + wvi * WR + mt * 16 + l15) *
                                              40 + quad * 8];
#pragma unroll
        for (int nt = 0; nt < 4; ++nt)
          acc[t][mt][nt] = __builtin_amdgcn_mfma_f32_16x16x32_bf16(
              a, bf[nt], acc[t][mt][nt], 0, 0, 0);
      }
    }
    __syncthreads();
  }

  float local = 0.0f;
#pragma unroll
  for (int mt = 0; mt < MT; ++mt)
#pragma unroll
    for (int nt = 0; nt < 4; ++nt)
#pragma unroll
      for (int reg = 0; reg < 4; ++reg)
        local += fabsf(acc[1][mt][nt][reg] - acc[0][mt][nt][reg]);
  float r = blk_sum256(local, s4);
  if (tid == 0) atomicAdd(&slots[3], r * fscale);
}

__global__ void combine_kernel(const float* __restrict__ slots,
                               float* __restrict__ out) {
  if (threadIdx.x == 0) {
    const float Nn = 1572864.0f;
    const float Nigt = 8388608.0f;
    out[0] = 2.0f * slots[0] / Nn + slots[1] / Nn + slots[2] / Nigt + slots[3];
  }
}

extern "C" void kernel_launch(void* const* d_in, const int* in_sizes, int n_in,
                              void* d_out, int out_size, void* d_ws,
                              size_t ws_size, hipStream_t stream) {
  (void)in_sizes; (void)n_in; (void)out_size;
  const float* igt = (const float*)d_in[0];
  const float* iout = (const float*)d_in[1];
  const float* mask = (const float*)d_in[2];
  const float* w[7];
  const float* b[7];
  for (int i = 0; i < 7; ++i) {
    w[i] = (const float*)d_in[3 + 2 * i];
    b[i] = (const float*)d_in[4 + 2 * i];
  }
  float* slots = (float*)d_ws;

  __hip_bfloat16* wpk = (__hip_bfloat16*)((char*)d_ws + 256);
  const long wpOff[6] = {0, 36864, 110592, 258048, 552960, 1142784};
  const int wpCin[6] = {64, 64, 128, 128, 256, 256};
  const int wpCout[6] = {64, 128, 128, 256, 256, 256};
  // weights end at byte 3,465,472

  // NB=2 tier needs 211,083,520 B; NB=1 needs 107,274,496 B (proven-safe)
  const size_t NEED2 = 211083520ULL;
  const int NB = (ws_size >= NEED2) ? 2 : 1;
  const int B3 = 3 * NB;

  char* base = (char*)d_ws + 3465472;
  __hip_bfloat16* bufA = (__hip_bfloat16*)base;                       // NB*33.55MB
  __hip_bfloat16* bufB = (__hip_bfloat16*)(base + (size_t)NB * 33554432);
  float* x0 = (float*)(base + (size_t)NB * 67108864);                 // NB*3.15MB
  __hip_bfloat16* P1N = (__hip_bfloat16*)(base + (size_t)NB * 70254592);  // 3NB imgs NHWC
  __hip_bfloat16* pgT1 = (__hip_bfloat16*)(base + (size_t)NB * 95420416); // NB planar
  __hip_bfloat16* pcT1 = bufA + (size_t)NB * 12582912;  // bufA tail (dead zone)
  // Batched-phase aliases (live ranges strictly sequential, r7-proven):
  __hip_bfloat16* T = bufA;                              // conv3 out
  __hip_bfloat16* P2N = P1N;                             // pooled L2 NHWC
  __hip_bfloat16* P2T = P1N + (size_t)NB * 6291456;      // planar L2
  __hip_bfloat16* Y5 = bufA;
  __hip_bfloat16* Y6 = bufA + (size_t)NB * 12582912;
  __hip_bfloat16* P3N = bufA + (size_t)NB * 25165824;
  __hip_bfloat16* P3T = pgT1;

  const float fs1 = (float)(1.0 / (4194304.0 * 4096.0));
  const float fs2 = (float)(1.0 / (2097152.0 * 16384.0));
  const float fs3 = (float)(1.0 / (1048576.0 * 65536.0));

  init_slots<<<1, 64, 0, stream>>>(slots);
  l1_kernel<<<304, 256, 0, stream>>>(igt, iout, mask, slots);
  for (int l = 0; l < 6; ++l) {
    int elems = wpCout[l] * wpCin[l] * 9;
    pack_w<<<(elems + 255) / 256, 256, 0, stream>>>(w[l + 1], wpk + wpOff[l],
                                                    wpCin[l], wpCout[l]);
  }

  for (int n0 = 0; n0 < 2; n0 += NB) {
    // ---- per-stream: conv1, conv2, pool1, perc1/gram1 ----
    for (int s = 0; s < 3; ++s) {
      pack_kernel<<<NB * 3072, 256, 0, stream>>>(igt, iout, mask, x0, s, n0, NB);
      conv1_k<<<dim3(16, 16, NB * 4), 256, 0, stream>>>(x0, w[0], b[0], bufA, 512, 512);
      conv_v4<<<dim3(8, 64, NB), 256, 0, stream>>>(
          bufA, wpk + wpOff[0], b[1], bufB, 64, 64, 512, 512);
      pool_k<<<dim3(32, 32, NB * 2), 256, 0, stream>>>(
          bufB, P1N + (size_t)s * NB * 4194304, (s ? pcT1 : pgT1), 64, 512, 512);
      if (s > 0) {
        perc_kernel<<<304, 256, 0, stream>>>(pgT1, pcT1, NB * 524288, slots);
        gram_mfma<128><<<dim3(4, 2, NB * 64), 256, 0, stream>>>(
            pgT1, pcT1, 256, 256, fs1, slots);
      }
    }
    // ---- batched over 3NB images: conv3..conv7, pools, perc/gram L2/L3 ----
    conv_v4<<<dim3(4, 32, B3 * 2), 256, 0, stream>>>(
        P1N, wpk + wpOff[1], b[2], T, 64, 128, 256, 256);
    conv_v4p<<<dim3(4, 32, B3 * 2), 256, 0, stream>>>(
        T, wpk + wpOff[2], b[3], P2N, 128, 128, 256, 256);
    transpose_k<<<dim3(16, 16, B3 * 4), 256, 0, stream>>>(P2N, P2T, 128, 128, 128);
    for (int s = 1; s <= 2; ++s) {
      perc_kernel<<<304, 256, 0, stream>>>(
          P2T, P2T + (size_t)s * NB * 2097152, NB * 262144, slots);
      gram_mfma<128><<<dim3(2, 1, NB * 128), 256, 0, stream>>>(
          P2T, P2T + (size_t)s * NB * 2097152, 128, 128, fs2, slots);
    }
    conv_v4<<<dim3(2, 16, B3 * 4), 256, 0, stream>>>(
        P2N, wpk + wpOff[3], b[4], Y5, 128, 256, 128, 128);
    conv_v4<<<dim3(2, 16, B3 * 4), 256, 0, stream>>>(
        Y5, wpk + wpOff[4], b[5], Y6, 256, 256, 128, 128);
    conv_v4p<<<dim3(2, 16, B3 * 4), 256, 0, stream>>>(
        Y6, wpk + wpOff[5], b[6], P3N, 256, 256, 128, 128);
    transpose_k<<<dim3(8, 8, B3 * 8), 256, 0, stream>>>(P3N, P3T, 256, 64, 64);
    for (int s = 1; s <= 2; ++s) {
      perc_kernel<<<304, 256, 0, stream>>>(
          P3T, P3T + (size_t)s * NB * 1048576, NB * 131072, slots);
      gram_mfma<64><<<dim3(1, 1, NB * 256), 256, 0, stream>>>(
          P3T, P3T + (size_t)s * NB * 1048576, 64, 64, fs3, slots);
    }
  }

  combine_kernel<<<1, 64, 0, stream>>>(slots, (float*)d_out);
}

// Round 10
// 1169.696 us; speedup vs baseline: 1.5619x; 1.0942x over previous
//
#include <hip/hip_runtime.h>
#include <hip/hip_bf16.h>

// ---------------------------------------------------------------------------
// VGG16 perceptual+style inpainting loss.
// conv1: MFMA via im2col-K32 packing (k = dy*9+dx*3+ci, 27 real + 5 pad).
// conv2..7: bf16 MFMA NHWC, A-tile + W-tile in LDS (r9-proven conv_v4/v4p).
// conv2/conv4/conv7 fuse 2x2 maxpool in-register. conv3..7 batched over the
// 3 streams. Gram: bf16 MFMA on col-major planar (transpose_k).
// Workspace: identical footprint to r9 (NB=2 needs 211.1MB, NB=1 107.3MB).
// ---------------------------------------------------------------------------

typedef __attribute__((ext_vector_type(8))) short bf16x8_t;
typedef __attribute__((ext_vector_type(4))) float f32x4_t;

__device__ __forceinline__ float b2f(__hip_bfloat16 v) {
  return __bfloat162float(v);
}

__device__ __forceinline__ float blk_sum256(float v, float* s4) {
#pragma unroll
  for (int o = 32; o > 0; o >>= 1) v += __shfl_down(v, o);
  int w = threadIdx.x >> 6;
  if ((threadIdx.x & 63) == 0) s4[w] = v;
  __syncthreads();
  float r = s4[0] + s4[1] + s4[2] + s4[3];
  __syncthreads();
  return r;
}

__global__ void init_slots(float* slots) {
  if (threadIdx.x < 8) slots[threadIdx.x] = 0.0f;
}

__global__ __launch_bounds__(256) void l1_kernel(
    const float* __restrict__ igt, const float* __restrict__ iout,
    const float* __restrict__ mask, float* __restrict__ slots) {
  __shared__ float s4[4];
  float ah = 0.0f, av = 0.0f;
  for (int idx = blockIdx.x * 256 + threadIdx.x; idx < 1572864;
       idx += gridDim.x * 256) {
    int pix = idx & 262143;
    int n = idx / 786432;
    float mk = mask[n * 262144 + pix];
    bool m = (mk != 0.0f);
    float d = fabsf(iout[idx] - igt[idx]);
    if (m) av += d; else ah += d;
  }
  float r = blk_sum256(ah, s4);
  if (threadIdx.x == 0) atomicAdd(&slots[0], r);
  r = blk_sum256(av, s4);
  if (threadIdx.x == 0) atomicAdd(&slots[1], r);
}

// Pack fp32 OIHW weights -> bf16 [tap][cout][cin] (conv2..7).
__global__ __launch_bounds__(256) void pack_w(const float* __restrict__ w,
                                              __hip_bfloat16* __restrict__ wp,
                                              int Cin, int Cout) {
  int i = blockIdx.x * 256 + threadIdx.x;
  if (i >= Cout * Cin * 9) return;
  int o = i % 9;
  int rem = i / 9;
  int ci = rem % Cin;
  int co = rem / Cin;
  wp[((long)(o * Cout + co)) * Cin + ci] = __float2bfloat16(w[i]);
}

// Pack conv1 weights [64][3][3][3] OIHW -> bf16 [co][32], k=dy*9+dx*3+ci.
__global__ __launch_bounds__(256) void pack_w1(const float* __restrict__ w,
                                               __hip_bfloat16* __restrict__ wk) {
  int i = blockIdx.x * 256 + threadIdx.x;
  if (i >= 64 * 32) return;
  int co = i >> 5, k = i & 31;
  float v = 0.0f;
  if (k < 27) {
    int dy = k / 9, r = k - dy * 9;
    int dx = r / 3, ci = r - dx * 3;
    v = w[((co * 3 + ci) * 3 + dy) * 3 + dx];
  }
  wk[i] = __float2bfloat16(v);
}

// Build im2col-K32 bf16 input Apk[nl][y][x][32] for stream sid.
// k = dy*9 + dx*3 + ci from source pixel (y-1+dy, x-1+dx), zero at borders.
__global__ __launch_bounds__(256) void pack2_kernel(
    const float* __restrict__ igt, const float* __restrict__ iout,
    const float* __restrict__ mask, __hip_bfloat16* __restrict__ apk, int sid,
    int n0, int NB) {
  int idx = blockIdx.x * 256 + threadIdx.x;
  if (idx >= NB * 262144) return;
  int nl = idx >> 18;
  int pix = idx & 262143;
  int y = pix >> 9, x = pix & 511;
  int sample = n0 + nl;
  __align__(16) __hip_bfloat16 buf[32];
#pragma unroll
  for (int k = 27; k < 32; ++k) buf[k] = __float2bfloat16(0.0f);
  for (int dy = 0; dy < 3; ++dy)
    for (int dx = 0; dx < 3; ++dx) {
      int gy = y - 1 + dy, gx = x - 1 + dx;
      bool inb = (gy >= 0 && gy < 512 && gx >= 0 && gx < 512);
      int p = gy * 512 + gx;
      bool useG;
      if (sid == 0) useG = true;
      else if (sid == 1) useG = false;
      else useG = inb && (mask[sample * 262144 + (inb ? p : 0)] != 0.0f);
      const float* src = useG ? igt : iout;
#pragma unroll
      for (int ci = 0; ci < 3; ++ci) {
        float v = inb ? src[sample * 786432 + ci * 262144 + p] : 0.0f;
        buf[dy * 9 + dx * 3 + ci] = __float2bfloat16(v);
      }
    }
  __hip_bfloat16* dst = apk + (long)idx * 32;
#pragma unroll
  for (int q = 0; q < 4; ++q)
    *(uint4*)&dst[q * 8] = *(const uint4*)&buf[q * 8];
}

// conv1 as single-chunk K=32 MFMA GEMM: Apk [n][512][512][32] x Wk[64][32]
// -> bf16 NHWC Y1 [n][512][512][64]. Block 256 = 4 waves; wave = 2 rows x
// 64 px x 64 co (m8n4). Grid (8, 64, NB).
__global__ __launch_bounds__(256, 2) void conv1m(
    const __hip_bfloat16* __restrict__ apk, const __hip_bfloat16* __restrict__ wk,
    const float* __restrict__ bias, __hip_bfloat16* __restrict__ out) {
  __shared__ __align__(16) short ApS[512 * 32];  // 8 rows x 64 px x 32 k
  __shared__ __align__(16) short BwS[64 * 32];
  const int tid = threadIdx.x;
  const int lane = tid & 63;
  const int wv = tid >> 6;
  const int quad = lane >> 4, l15 = lane & 15;
  const int n = blockIdx.z;
  const int x0 = blockIdx.x << 6;
  const int y0 = blockIdx.y << 3;

  for (int e = tid; e < 2048; e += 256) {  // 512 px * 4 chunks
    int q = e & 3, pos = e >> 2;
    int r = pos >> 6, c = pos & 63;
    *(uint4*)&ApS[pos * 32 + q * 8] =
        *(const uint4*)(apk + (((long)n * 512 + y0 + r) * 512 + x0 + c) * 32 +
                        q * 8);
  }
  if (tid < 256) {  // 64 co * 4 chunks
    int q = tid & 3, co = tid >> 2;
    *(uint4*)&BwS[co * 32 + q * 8] = *(const uint4*)(wk + co * 32 + q * 8);
  }
  __syncthreads();

  f32x4_t acc[8][4];
#pragma unroll
  for (int mt = 0; mt < 8; ++mt)
#pragma unroll
    for (int nt = 0; nt < 4; ++nt) acc[mt][nt] = (f32x4_t)0.0f;

  bf16x8_t bf[4];
#pragma unroll
  for (int nt = 0; nt < 4; ++nt)
    bf[nt] = *(const bf16x8_t*)&BwS[(nt * 16 + l15) * 32 + quad * 8];
#pragma unroll
  for (int mt = 0; mt < 8; ++mt) {
    const int rl = 2 * wv + (mt >> 2);
    const int pl = (mt & 3) * 16 + l15;
    const bf16x8_t a = *(const bf16x8_t*)&ApS[(rl * 64 + pl) * 32 + quad * 8];
#pragma unroll
    for (int nt = 0; nt < 4; ++nt)
      acc[mt][nt] = __builtin_amdgcn_mfma_f32_16x16x32_bf16(a, bf[nt],
                                                            acc[mt][nt], 0, 0, 0);
  }

  float bv[4];
#pragma unroll
  for (int nt = 0; nt < 4; ++nt) bv[nt] = bias[nt * 16 + l15];
#pragma unroll
  for (int mt = 0; mt < 8; ++mt) {
    const int y = y0 + 2 * wv + (mt >> 2);
#pragma unroll
    for (int nt = 0; nt < 4; ++nt) {
      const int col = nt * 16 + l15;
#pragma unroll
      for (int reg = 0; reg < 4; ++reg) {
        int px = (mt & 3) * 16 + quad * 4 + reg;
        float v = fmaxf(acc[mt][nt][reg] + bv[nt], 0.0f);
        out[(((long)n * 512 + y) * 512 + x0 + px) * 64 + col] =
            __float2bfloat16(v);
      }
    }
  }
}

// ---------------------------------------------------------------------------
// conv_v4: MFMA 3x3 conv, bias+relu, bf16 NHWC. A-tile + W-tile in LDS.
// Block 256 = 4 waves; wave = 2 rows x 64 px x 64 co (m8n4). (r9-proven)
// ---------------------------------------------------------------------------
__global__ __launch_bounds__(256, 2) void conv_v4(
    const __hip_bfloat16* __restrict__ act,
    const __hip_bfloat16* __restrict__ wp, const float* __restrict__ bias,
    __hip_bfloat16* __restrict__ out, int Cin, int Cout, int H, int W) {
  __shared__ __align__(16) short ApS[2640 * 8];
  __shared__ __align__(16) short BwS[2304 * 8];
  const int tid = threadIdx.x;
  const int lane = tid & 63;
  const int wv = tid >> 6;
  const int quad = lane >> 4, l15 = lane & 15;
  const int coB = Cout >> 6;
  const int n = blockIdx.z / coB;
  const int co0 = (blockIdx.z % coB) << 6;
  const int x0 = blockIdx.x << 6;
  const int y0 = blockIdx.y << 3;

  f32x4_t acc[8][4];
#pragma unroll
  for (int mt = 0; mt < 8; ++mt)
#pragma unroll
    for (int nt = 0; nt < 4; ++nt) acc[mt][nt] = (f32x4_t)0.0f;

  for (int cb = 0; cb < Cin; cb += 32) {
    for (int e = tid; e < 2640; e += 256) {
      int q = e & 3, pos = e >> 2;
      int r = pos / 66, c = pos - r * 66;
      int gy = y0 - 1 + r, gx = x0 - 1 + c;
      uint4 v = make_uint4(0, 0, 0, 0);
      if (gy >= 0 && gy < H && gx >= 0 && gx < W)
        v = *(const uint4*)(act + (((long)n * H + gy) * W + gx) * Cin + cb +
                            q * 8);
      *(uint4*)&ApS[pos * 32 + q * 8] = v;
    }
    for (int e = tid; e < 2304; e += 256) {
      int q = e & 3, idx = e >> 2;
      int o = idx >> 6, co = idx & 63;
      *(uint4*)&BwS[idx * 32 + q * 8] =
          *(const uint4*)(wp + ((long)(o * Cout + co0 + co)) * Cin + cb +
                          q * 8);
    }
    __syncthreads();

#pragma unroll
    for (int o = 0; o < 9; ++o) {
      const int dy = o / 3, dx = o % 3;
      bf16x8_t bf[4];
#pragma unroll
      for (int nt = 0; nt < 4; ++nt)
        bf[nt] = *(const bf16x8_t*)&BwS[((o << 6) + nt * 16 + l15) * 32 +
                                        quad * 8];
#pragma unroll
      for (int mt = 0; mt < 8; ++mt) {
        const int rl = 2 * wv + (mt >> 2) + dy;
        const int pl = (mt & 3) * 16 + l15 + dx;
        const bf16x8_t a =
            *(const bf16x8_t*)&ApS[(rl * 66 + pl) * 32 + quad * 8];
#pragma unroll
        for (int nt = 0; nt < 4; ++nt)
          acc[mt][nt] = __builtin_amdgcn_mfma_f32_16x16x32_bf16(
              a, bf[nt], acc[mt][nt], 0, 0, 0);
      }
    }
    __syncthreads();
  }

  float bv[4];
#pragma unroll
  for (int nt = 0; nt < 4; ++nt) bv[nt] = bias[co0 + nt * 16 + l15];
#pragma unroll
  for (int mt = 0; mt < 8; ++mt) {
    const int y = y0 + 2 * wv + (mt >> 2);
#pragma unroll
    for (int nt = 0; nt < 4; ++nt) {
      const int col = co0 + nt * 16 + l15;
#pragma unroll
      for (int reg = 0; reg < 4; ++reg) {
        int px = (mt & 3) * 16 + quad * 4 + reg;
        float v = fmaxf(acc[mt][nt][reg] + bv[nt], 0.0f);
        out[(((long)n * H + y) * W + x0 + px) * Cout + col] =
            __float2bfloat16(v);
      }
    }
  }
}

// conv_v4p: conv_v4 + fused 2x2 maxpool (r9-proven).
__global__ __launch_bounds__(256, 2) void conv_v4p(
    const __hip_bfloat16* __restrict__ act,
    const __hip_bfloat16* __restrict__ wp, const float* __restrict__ bias,
    __hip_bfloat16* __restrict__ out, int Cin, int Cout, int H, int W) {
  __shared__ __align__(16) short ApS[2640 * 8];
  __shared__ __align__(16) short BwS[2304 * 8];
  const int tid = threadIdx.x;
  const int lane = tid & 63;
  const int wv = tid >> 6;
  const int quad = lane >> 4, l15 = lane & 15;
  const int coB = Cout >> 6;
  const int n = blockIdx.z / coB;
  const int co0 = (blockIdx.z % coB) << 6;
  const int x0g = blockIdx.x << 6;
  const int y0 = blockIdx.y << 3;

  f32x4_t acc[8][4];
#pragma unroll
  for (int mt = 0; mt < 8; ++mt)
#pragma unroll
    for (int nt = 0; nt < 4; ++nt) acc[mt][nt] = (f32x4_t)0.0f;

  for (int cb = 0; cb < Cin; cb += 32) {
    for (int e = tid; e < 2640; e += 256) {
      int q = e & 3, pos = e >> 2;
      int r = pos / 66, c = pos - r * 66;
      int gy = y0 - 1 + r, gx = x0g - 1 + c;
      uint4 v = make_uint4(0, 0, 0, 0);
      if (gy >= 0 && gy < H && gx >= 0 && gx < W)
        v = *(const uint4*)(act + (((long)n * H + gy) * W + gx) * Cin + cb +
                            q * 8);
      *(uint4*)&ApS[pos * 32 + q * 8] = v;
    }
    for (int e = tid; e < 2304; e += 256) {
      int q = e & 3, idx = e >> 2;
      int o = idx >> 6, co = idx & 63;
      *(uint4*)&BwS[idx * 32 + q * 8] =
          *(const uint4*)(wp + ((long)(o * Cout + co0 + co)) * Cin + cb +
                          q * 8);
    }
    __syncthreads();

#pragma unroll
    for (int o = 0; o < 9; ++o) {
      const int dy = o / 3, dx = o % 3;
      bf16x8_t bf[4];
#pragma unroll
      for (int nt = 0; nt < 4; ++nt)
        bf[nt] = *(const bf16x8_t*)&BwS[((o << 6) + nt * 16 + l15) * 32 +
                                        quad * 8];
#pragma unroll
      for (int mt = 0; mt < 8; ++mt) {
        const int rl = 2 * wv + (mt >> 2) + dy;
        const int pl = (mt & 3) * 16 + l15 + dx;
        const bf16x8_t a =
            *(const bf16x8_t*)&ApS[(rl * 66 + pl) * 32 + quad * 8];
#pragma unroll
        for (int nt = 0; nt < 4; ++nt)
          acc[mt][nt] = __builtin_amdgcn_mfma_f32_16x16x32_bf16(
              a, bf[nt], acc[mt][nt], 0, 0, 0);
      }
    }
    __syncthreads();
  }

  const int Ho = H >> 1, Wo = W >> 1;
  const int ho = (blockIdx.y << 2) + wv;
  float bv[4];
#pragma unroll
  for (int nt = 0; nt < 4; ++nt) bv[nt] = bias[co0 + nt * 16 + l15];
#pragma unroll
  for (int mtA = 0; mtA < 4; ++mtA)
#pragma unroll
    for (int nt = 0; nt < 4; ++nt) {
      const int col = co0 + nt * 16 + l15;
#pragma unroll
      for (int half = 0; half < 2; ++half) {
        float m0 = fmaxf(
            fmaxf(acc[mtA][nt][2 * half], acc[mtA][nt][2 * half + 1]),
            fmaxf(acc[mtA + 4][nt][2 * half], acc[mtA + 4][nt][2 * half + 1]));
        float v = fmaxf(m0 + bv[nt], 0.0f);
        int wo = (blockIdx.x << 5) + mtA * 8 + quad * 2 + half;
        out[(((long)n * Ho + ho) * Wo + wo) * Cout + col] = __float2bfloat16(v);
      }
    }
}

// NHWC [j][Ho][Wo][C] -> col-major planar [(j*C+c)][Wo][Ho].
__global__ __launch_bounds__(256) void transpose_k(
    const __hip_bfloat16* __restrict__ in, __hip_bfloat16* __restrict__ out,
    int C, int Ho, int Wo) {
  const int cl = threadIdx.x & 31;
  const int wl = threadIdx.x >> 5;
  const int cg = C >> 5;
  const int j = blockIdx.z / cg;
  const int c = (blockIdx.z % cg) * 32 + cl;
  const int wo = blockIdx.x * 8 + wl;
  const int ho0 = blockIdx.y * 8;
  __align__(16) __hip_bfloat16 res[8];
#pragma unroll
  for (int i = 0; i < 8; ++i)
    res[i] = in[(((long)j * Ho + ho0 + i) * Wo + wo) * C + c];
  *(uint4*)&out[((long)(j * C + c) * Wo + wo) * Ho + ho0] =
      *(const uint4*)res;
}

// l_perc partial: sum |cur - gt| over 8*M8 bf16 elements -> slots[2]
__global__ __launch_bounds__(256) void perc_kernel(
    const __hip_bfloat16* __restrict__ gt, const __hip_bfloat16* __restrict__ cur,
    int M8, float* __restrict__ slots) {
  __shared__ float s4[4];
  const uint4* g4 = (const uint4*)gt;
  const uint4* c4 = (const uint4*)cur;
  float acc = 0.0f;
  for (int i = blockIdx.x * 256 + threadIdx.x; i < M8; i += gridDim.x * 256) {
    uint4 g = g4[i], c = c4[i];
    const unsigned* gu = (const unsigned*)&g;
    const unsigned* cu = (const unsigned*)&c;
#pragma unroll
    for (int k = 0; k < 4; ++k) {
      float g0 = __uint_as_float(gu[k] << 16);
      float g1 = __uint_as_float(gu[k] & 0xffff0000u);
      float c0 = __uint_as_float(cu[k] << 16);
      float c1 = __uint_as_float(cu[k] & 0xffff0000u);
      acc += fabsf(c0 - g0) + fabsf(c1 - g1);
    }
  }
  float r = blk_sum256(acc, s4);
  if (threadIdx.x == 0) atomicAdd(&slots[2], r);
}

// Style partial via bf16 MFMA (r5-proven). Inputs col-major planar bf16.
template <int BM>
__global__ __launch_bounds__(256) void gram_mfma(
    const __hip_bfloat16* __restrict__ gt_p,
    const __hip_bfloat16* __restrict__ cur_p, int Wp, int Hp, float fscale,
    float* __restrict__ slots) {
  constexpr int COLS = BM + 64;
  constexpr int WR = BM / 4;
  constexpr int MT = WR / 16;
  __shared__ __align__(16) short S[2 * COLS * 40];
  __shared__ float s4[4];
  const int tid = threadIdx.x;
  const int lane = tid & 63;
  const int wvi = tid >> 6;
  const int quad = lane >> 4, l15 = lane & 15;
  const int vt = blockIdx.x * 64;
  const int wt = blockIdx.y * BM;
  const long plane = (long)blockIdx.z * Wp * Hp;
  const __hip_bfloat16* bases[2] = {gt_p + plane, cur_p + plane};

  f32x4_t acc[2][MT][4];
#pragma unroll
  for (int t = 0; t < 2; ++t)
#pragma unroll
    for (int mt = 0; mt < MT; ++mt)
#pragma unroll
      for (int nt = 0; nt < 4; ++nt) acc[t][mt][nt] = (f32x4_t)0.0f;

  const int nchunk = 2 * COLS * 4;
  for (int h0 = 0; h0 < Hp; h0 += 32) {
    for (int e = tid; e < nchunk; e += 256) {
      int chunk = e & 3;
      int colt = e >> 2;
      int t = colt / COLS;
      int col = colt - t * COLS;
      int sc = (col < BM) ? (wt + col) : (vt + col - BM);
      uint4 v = *(const uint4*)(bases[t] + (long)sc * Hp + h0 + chunk * 8);
      *(uint4*)&S[(t * COLS + col) * 40 + chunk * 8] = v;
    }
    __syncthreads();
#pragma unroll
    for (int t = 0; t < 2; ++t) {
      bf16x8_t bf[4];
#pragma unroll
      for (int nt = 0; nt < 4; ++nt)
        bf[nt] = *(const bf16x8_t*)&S[(t * COLS + BM + nt * 16 + l15) * 40 +
                                      quad * 8];
#pragma unroll
      for (int mt = 0; mt < MT; ++mt) {
        bf16x8_t a = *(const bf16x8_t*)&S[(t * COLS + wvi * WR + mt * 16 + l15) *
                                              40 + quad * 8];
#pragma unroll
        for (int nt = 0; nt < 4; ++nt)
          acc[t][mt][nt] = __builtin_amdgcn_mfma_f32_16x16x32_bf16(
              a, bf[nt], acc[t][mt][nt], 0, 0, 0);
      }
    }
    __syncthreads();
  }

  float local = 0.0f;
#pragma unroll
  for (int mt = 0; mt < MT; ++mt)
#pragma unroll
    for (int nt = 0; nt < 4; ++nt)
#pragma unroll
      for (int reg = 0; reg < 4; ++reg)
        local += fabsf(acc[1][mt][nt][reg] - acc[0][mt][nt][reg]);
  float r = blk_sum256(local, s4);
  if (tid == 0) atomicAdd(&slots[3], r * fscale);
}

__global__ void combine_kernel(const float* __restrict__ slots,
                               float* __restrict__ out) {
  if (threadIdx.x == 0) {
    const float Nn = 1572864.0f;
    const float Nigt = 8388608.0f;
    out[0] = 2.0f * slots[0] / Nn + slots[1] / Nn + slots[2] / Nigt + slots[3];
  }
}

extern "C" void kernel_launch(void* const* d_in, const int* in_sizes, int n_in,
                              void* d_out, int out_size, void* d_ws,
                              size_t ws_size, hipStream_t stream) {
  (void)in_sizes; (void)n_in; (void)out_size;
  const float* igt = (const float*)d_in[0];
  const float* iout = (const float*)d_in[1];
  const float* mask = (const float*)d_in[2];
  const float* w[7];
  const float* b[7];
  for (int i = 0; i < 7; ++i) {
    w[i] = (const float*)d_in[3 + 2 * i];
    b[i] = (const float*)d_in[4 + 2 * i];
  }
  float* slots = (float*)d_ws;

  __hip_bfloat16* wpk = (__hip_bfloat16*)((char*)d_ws + 256);
  const long wpOff[6] = {0, 36864, 110592, 258048, 552960, 1142784};
  const int wpCin[6] = {64, 64, 128, 128, 256, 256};
  const int wpCout[6] = {64, 128, 128, 256, 256, 256};
  // weights end at byte 3,465,472

  const size_t NEED2 = 211083520ULL;
  const int NB = (ws_size >= NEED2) ? 2 : 1;
  const int B3 = 3 * NB;

  char* base = (char*)d_ws + 3465472;
  __hip_bfloat16* bufA = (__hip_bfloat16*)base;                       // NB*33.55MB
  __hip_bfloat16* Apk = (__hip_bfloat16*)(base + (size_t)NB * 33554432);  // im2col (bufB slot)
  __hip_bfloat16* w1k = (__hip_bfloat16*)(base + (size_t)NB * 67108864);  // conv1 wk (old x0 slot)
  __hip_bfloat16* P1N = (__hip_bfloat16*)(base + (size_t)NB * 70254592);  // 3NB pooled L1 NHWC
  __hip_bfloat16* pgT1 = (__hip_bfloat16*)(base + (size_t)NB * 95420416); // NB planar
  __hip_bfloat16* pcT1 = bufA + (size_t)NB * 12582912;  // bufA tail (Y1 dead by then)
  // Batched-phase aliases (live ranges strictly sequential, r9-proven):
  __hip_bfloat16* T = bufA;
  __hip_bfloat16* P2N = P1N;
  __hip_bfloat16* P2T = P1N + (size_t)NB * 6291456;
  __hip_bfloat16* Y5 = bufA;
  __hip_bfloat16* Y6 = bufA + (size_t)NB * 12582912;
  __hip_bfloat16* P3N = bufA + (size_t)NB * 25165824;
  __hip_bfloat16* P3T = pgT1;

  const float fs1 = (float)(1.0 / (4194304.0 * 4096.0));
  const float fs2 = (float)(1.0 / (2097152.0 * 16384.0));
  const float fs3 = (float)(1.0 / (1048576.0 * 65536.0));

  init_slots<<<1, 64, 0, stream>>>(slots);
  l1_kernel<<<304, 256, 0, stream>>>(igt, iout, mask, slots);
  for (int l = 0; l < 6; ++l) {
    int elems = wpCout[l] * wpCin[l] * 9;
    pack_w<<<(elems + 255) / 256, 256, 0, stream>>>(w[l + 1], wpk + wpOff[l],
                                                    wpCin[l], wpCout[l]);
  }
  pack_w1<<<8, 256, 0, stream>>>(w[0], w1k);

  for (int n0 = 0; n0 < 2; n0 += NB) {
    // ---- per-stream front end: pack -> conv1(MFMA) -> conv2+pool -> gram1 --
    for (int s = 0; s < 3; ++s) {
      __hip_bfloat16* slot = P1N + (size_t)s * NB * 4194304;
      pack2_kernel<<<NB * 1024, 256, 0, stream>>>(igt, iout, mask, Apk, s, n0, NB);
      conv1m<<<dim3(8, 64, NB), 256, 0, stream>>>(Apk, w1k, b[0], bufA);
      conv_v4p<<<dim3(8, 64, NB), 256, 0, stream>>>(
          bufA, wpk + wpOff[0], b[1], slot, 64, 64, 512, 512);
      transpose_k<<<dim3(32, 32, NB * 2), 256, 0, stream>>>(
          slot, (s ? pcT1 : pgT1), 64, 256, 256);
      if (s > 0) {
        perc_kernel<<<304, 256, 0, stream>>>(pgT1, pcT1, NB * 524288, slots);
        gram_mfma<128><<<dim3(4, 2, NB * 64), 256, 0, stream>>>(
            pgT1, pcT1, 256, 256, fs1, slots);
      }
    }
    // ---- batched over 3NB images: conv3..conv7, perc/gram L2/L3 ----
    conv_v4<<<dim3(4, 32, B3 * 2), 256, 0, stream>>>(
        P1N, wpk + wpOff[1], b[2], T, 64, 128, 256, 256);
    conv_v4p<<<dim3(4, 32, B3 * 2), 256, 0, stream>>>(
        T, wpk + wpOff[2], b[3], P2N, 128, 128, 256, 256);
    transpose_k<<<dim3(16, 16, B3 * 4), 256, 0, stream>>>(P2N, P2T, 128, 128, 128);
    for (int s = 1; s <= 2; ++s) {
      perc_kernel<<<304, 256, 0, stream>>>(
          P2T, P2T + (size_t)s * NB * 2097152, NB * 262144, slots);
      gram_mfma<128><<<dim3(2, 1, NB * 128), 256, 0, stream>>>(
          P2T, P2T + (size_t)s * NB * 2097152, 128, 128, fs2, slots);
    }
    conv_v4<<<dim3(2, 16, B3 * 4), 256, 0, stream>>>(
        P2N, wpk + wpOff[3], b[4], Y5, 128, 256, 128, 128);
    conv_v4<<<dim3(2, 16, B3 * 4), 256, 0, stream>>>(
        Y5, wpk + wpOff[4], b[5], Y6, 256, 256, 128, 128);
    conv_v4p<<<dim3(2, 16, B3 * 4), 256, 0, stream>>>(
        Y6, wpk + wpOff[5], b[6], P3N, 256, 256, 128, 128);
    transpose_k<<<dim3(8, 8, B3 * 8), 256, 0, stream>>>(P3N, P3T, 256, 64, 64);
    for (int s = 1; s <= 2; ++s) {
      perc_kernel<<<304, 256, 0, stream>>>(
          P3T, P3T + (size_t)s * NB * 1048576, NB * 131072, slots);
      gram_mfma<64><<<dim3(1, 1, NB * 256), 256, 0, stream>>>(
          P3T, P3T + (size_t)s * NB * 1048576, 64, 64, fs3, slots);
    }
  }

  combine_kernel<<<1, 64, 0, stream>>>(slots, (float*)d_out);
}

// Round 11
// 981.392 us; speedup vs baseline: 1.8616x; 1.1919x over previous
//
#include <hip/hip_runtime.h>
#include <hip/hip_bf16.h>

// ---------------------------------------------------------------------------
// VGG16 perceptual+style inpainting loss.
// conv1: bf16 MFMA via im2col-K32 (r10-proven) -> fp8 output.
// conv2..7: fp8(e4m3) MFMA NHWC, A-tile + W-tile in LDS (r9 tile geometry,
// half the bytes). Pool epilogues dual-store fp8 (conv chain) + bf16
// (gram/perc path). Gram: bf16 MFMA on col-major planar. l1/perc grid-stride.
// Workspace: NEED2 = 194.7MB (<=211 proven), NEED1 = 98.2MB (<=116.4 proven).
// ---------------------------------------------------------------------------

typedef __attribute__((ext_vector_type(8))) short bf16x8_t;
typedef __attribute__((ext_vector_type(4))) float f32x4_t;

__device__ __forceinline__ float b2f(__hip_bfloat16 v) {
  return __bfloat162float(v);
}

__device__ __forceinline__ unsigned char f2fp8(float v) {
  return (unsigned char)(__builtin_amdgcn_cvt_pk_fp8_f32(v, v, 0, false) & 0xff);
}

__device__ __forceinline__ float blk_sum256(float v, float* s4) {
#pragma unroll
  for (int o = 32; o > 0; o >>= 1) v += __shfl_down(v, o);
  int w = threadIdx.x >> 6;
  if ((threadIdx.x & 63) == 0) s4[w] = v;
  __syncthreads();
  float r = s4[0] + s4[1] + s4[2] + s4[3];
  __syncthreads();
  return r;
}

__global__ void init_slots(float* slots) {
  if (threadIdx.x < 8) slots[threadIdx.x] = 0.0f;
}

__global__ __launch_bounds__(256) void l1_kernel(
    const float* __restrict__ igt, const float* __restrict__ iout,
    const float* __restrict__ mask, float* __restrict__ slots) {
  __shared__ float s4[4];
  float ah = 0.0f, av = 0.0f;
  for (int idx = blockIdx.x * 256 + threadIdx.x; idx < 1572864;
       idx += gridDim.x * 256) {
    int pix = idx & 262143;
    int n = idx / 786432;
    float mk = mask[n * 262144 + pix];
    bool m = (mk != 0.0f);
    float d = fabsf(iout[idx] - igt[idx]);
    if (m) av += d; else ah += d;
  }
  float r = blk_sum256(ah, s4);
  if (threadIdx.x == 0) atomicAdd(&slots[0], r);
  r = blk_sum256(av, s4);
  if (threadIdx.x == 0) atomicAdd(&slots[1], r);
}

// Pack fp32 OIHW weights -> fp8 e4m3 [tap][cout][cin] (conv2..7).
__global__ __launch_bounds__(256) void pack_w(const float* __restrict__ w,
                                              unsigned char* __restrict__ wp,
                                              int Cin, int Cout) {
  int i = blockIdx.x * 256 + threadIdx.x;
  if (i >= Cout * Cin * 9) return;
  int o = i % 9;
  int rem = i / 9;
  int ci = rem % Cin;
  int co = rem / Cin;
  wp[((long)(o * Cout + co)) * Cin + ci] = f2fp8(w[i]);
}

// Pack conv1 weights [64][3][3][3] OIHW -> bf16 [co][32], k=dy*9+dx*3+ci.
__global__ __launch_bounds__(256) void pack_w1(const float* __restrict__ w,
                                               __hip_bfloat16* __restrict__ wk) {
  int i = blockIdx.x * 256 + threadIdx.x;
  if (i >= 64 * 32) return;
  int co = i >> 5, k = i & 31;
  float v = 0.0f;
  if (k < 27) {
    int dy = k / 9, r = k - dy * 9;
    int dx = r / 3, ci = r - dx * 3;
    v = w[((co * 3 + ci) * 3 + dy) * 3 + dx];
  }
  wk[i] = __float2bfloat16(v);
}

// Build im2col-K32 bf16 input Apk[nl][y][x][32] for stream sid. (r10-proven)
__global__ __launch_bounds__(256) void pack2_kernel(
    const float* __restrict__ igt, const float* __restrict__ iout,
    const float* __restrict__ mask, __hip_bfloat16* __restrict__ apk, int sid,
    int n0, int NB) {
  int idx = blockIdx.x * 256 + threadIdx.x;
  if (idx >= NB * 262144) return;
  int nl = idx >> 18;
  int pix = idx & 262143;
  int y = pix >> 9, x = pix & 511;
  int sample = n0 + nl;
  __align__(16) __hip_bfloat16 buf[32];
#pragma unroll
  for (int k = 27; k < 32; ++k) buf[k] = __float2bfloat16(0.0f);
  for (int dy = 0; dy < 3; ++dy)
    for (int dx = 0; dx < 3; ++dx) {
      int gy = y - 1 + dy, gx = x - 1 + dx;
      bool inb = (gy >= 0 && gy < 512 && gx >= 0 && gx < 512);
      int p = gy * 512 + gx;
      bool useG;
      if (sid == 0) useG = true;
      else if (sid == 1) useG = false;
      else useG = inb && (mask[sample * 262144 + (inb ? p : 0)] != 0.0f);
      const float* src = useG ? igt : iout;
#pragma unroll
      for (int ci = 0; ci < 3; ++ci) {
        float v = inb ? src[sample * 786432 + ci * 262144 + p] : 0.0f;
        buf[dy * 9 + dx * 3 + ci] = __float2bfloat16(v);
      }
    }
  __hip_bfloat16* dst = apk + (long)idx * 32;
#pragma unroll
  for (int q = 0; q < 4; ++q)
    *(uint4*)&dst[q * 8] = *(const uint4*)&buf[q * 8];
}

// conv1: single-chunk K=32 bf16 MFMA GEMM -> fp8 NHWC Y1. (r10-proven core)
__global__ __launch_bounds__(256, 2) void conv1m(
    const __hip_bfloat16* __restrict__ apk, const __hip_bfloat16* __restrict__ wk,
    const float* __restrict__ bias, unsigned char* __restrict__ out) {
  __shared__ __align__(16) short ApS[512 * 32];
  __shared__ __align__(16) short BwS[64 * 32];
  const int tid = threadIdx.x;
  const int lane = tid & 63;
  const int wv = tid >> 6;
  const int quad = lane >> 4, l15 = lane & 15;
  const int n = blockIdx.z;
  const int x0 = blockIdx.x << 6;
  const int y0 = blockIdx.y << 3;

  for (int e = tid; e < 2048; e += 256) {
    int q = e & 3, pos = e >> 2;
    int r = pos >> 6, c = pos & 63;
    *(uint4*)&ApS[pos * 32 + q * 8] =
        *(const uint4*)(apk + (((long)n * 512 + y0 + r) * 512 + x0 + c) * 32 +
                        q * 8);
  }
  if (tid < 256) {
    int q = tid & 3, co = tid >> 2;
    *(uint4*)&BwS[co * 32 + q * 8] = *(const uint4*)(wk + co * 32 + q * 8);
  }
  __syncthreads();

  f32x4_t acc[8][4];
#pragma unroll
  for (int mt = 0; mt < 8; ++mt)
#pragma unroll
    for (int nt = 0; nt < 4; ++nt) acc[mt][nt] = (f32x4_t)0.0f;

  bf16x8_t bf[4];
#pragma unroll
  for (int nt = 0; nt < 4; ++nt)
    bf[nt] = *(const bf16x8_t*)&BwS[(nt * 16 + l15) * 32 + quad * 8];
#pragma unroll
  for (int mt = 0; mt < 8; ++mt) {
    const int rl = 2 * wv + (mt >> 2);
    const int pl = (mt & 3) * 16 + l15;
    const bf16x8_t a = *(const bf16x8_t*)&ApS[(rl * 64 + pl) * 32 + quad * 8];
#pragma unroll
    for (int nt = 0; nt < 4; ++nt)
      acc[mt][nt] = __builtin_amdgcn_mfma_f32_16x16x32_bf16(a, bf[nt],
                                                            acc[mt][nt], 0, 0, 0);
  }

  float bv[4];
#pragma unroll
  for (int nt = 0; nt < 4; ++nt) bv[nt] = bias[nt * 16 + l15];
#pragma unroll
  for (int mt = 0; mt < 8; ++mt) {
    const int y = y0 + 2 * wv + (mt >> 2);
#pragma unroll
    for (int nt = 0; nt < 4; ++nt) {
      const int col = nt * 16 + l15;
#pragma unroll
      for (int reg = 0; reg < 4; ++reg) {
        int px = (mt & 3) * 16 + quad * 4 + reg;
        float v = fmaxf(acc[mt][nt][reg] + bv[nt], 0.0f);
        out[(((long)n * 512 + y) * 512 + x0 + px) * 64 + col] = f2fp8(v);
      }
    }
  }
}

// ---------------------------------------------------------------------------
// conv_f8: fp8 MFMA 3x3 conv, bias+relu, fp8 NHWC. A+W tiles in LDS.
// Wave = 2 rows x 64 px x 64 co (m8n4), identical tile geometry to r9's
// conv_v4 with byte elements. LDS: A 21,120B + W 18,432B.
// ---------------------------------------------------------------------------
__global__ __launch_bounds__(256, 2) void conv_f8(
    const unsigned char* __restrict__ act, const unsigned char* __restrict__ wp,
    const float* __restrict__ bias, unsigned char* __restrict__ out, int Cin,
    int Cout, int H, int W) {
  __shared__ __align__(16) unsigned char ApS[660 * 32];
  __shared__ __align__(16) unsigned char BwS[576 * 32];
  const int tid = threadIdx.x;
  const int lane = tid & 63;
  const int wv = tid >> 6;
  const int quad = lane >> 4, l15 = lane & 15;
  const int coB = Cout >> 6;
  const int n = blockIdx.z / coB;
  const int co0 = (blockIdx.z % coB) << 6;
  const int x0 = blockIdx.x << 6;
  const int y0 = blockIdx.y << 3;

  f32x4_t acc[8][4];
#pragma unroll
  for (int mt = 0; mt < 8; ++mt)
#pragma unroll
    for (int nt = 0; nt < 4; ++nt) acc[mt][nt] = (f32x4_t)0.0f;

  for (int cb = 0; cb < Cin; cb += 32) {
    for (int e = tid; e < 1320; e += 256) {  // A: 10*66 px * 2 chunks(16B)
      int q = e & 1, pos = e >> 1;
      int r = pos / 66, c = pos - r * 66;
      int gy = y0 - 1 + r, gx = x0 - 1 + c;
      uint4 v = make_uint4(0, 0, 0, 0);
      if (gy >= 0 && gy < H && gx >= 0 && gx < W)
        v = *(const uint4*)(act + ((long)((long)n * H + gy) * W + gx) * Cin +
                            cb + q * 16);
      *(uint4*)&ApS[pos * 32 + q * 16] = v;
    }
    for (int e = tid; e < 1152; e += 256) {  // W: 9*64 * 2 chunks
      int q = e & 1, idx = e >> 1;
      int o = idx >> 6, co = idx & 63;
      *(uint4*)&BwS[idx * 32 + q * 16] =
          *(const uint4*)(wp + ((long)(o * Cout + co0 + co)) * Cin + cb +
                          q * 16);
    }
    __syncthreads();

#pragma unroll
    for (int o = 0; o < 9; ++o) {
      const int dy = o / 3, dx = o % 3;
      long long bf[4];
#pragma unroll
      for (int nt = 0; nt < 4; ++nt)
        bf[nt] = *(const long long*)&BwS[((o << 6) + nt * 16 + l15) * 32 +
                                         quad * 8];
#pragma unroll
      for (int mt = 0; mt < 8; ++mt) {
        const int rl = 2 * wv + (mt >> 2) + dy;
        const int pl = (mt & 3) * 16 + l15 + dx;
        const long long a =
            *(const long long*)&ApS[(rl * 66 + pl) * 32 + quad * 8];
#pragma unroll
        for (int nt = 0; nt < 4; ++nt)
          acc[mt][nt] = __builtin_amdgcn_mfma_f32_16x16x32_fp8_fp8(
              a, bf[nt], acc[mt][nt], 0, 0, 0);
      }
    }
    __syncthreads();
  }

  float bv[4];
#pragma unroll
  for (int nt = 0; nt < 4; ++nt) bv[nt] = bias[co0 + nt * 16 + l15];
#pragma unroll
  for (int mt = 0; mt < 8; ++mt) {
    const int y = y0 + 2 * wv + (mt >> 2);
#pragma unroll
    for (int nt = 0; nt < 4; ++nt) {
      const int col = co0 + nt * 16 + l15;
#pragma unroll
      for (int reg = 0; reg < 4; ++reg) {
        int px = (mt & 3) * 16 + quad * 4 + reg;
        float v = fmaxf(acc[mt][nt][reg] + bv[nt], 0.0f);
        out[(((long)n * H + y) * W + x0 + px) * Cout + col] = f2fp8(v);
      }
    }
  }
}

// conv_f8p: conv_f8 + fused 2x2 maxpool, dual-store: fp8 NHWC (conv chain)
// + bf16 NHWC (gram/perc path).
__global__ __launch_bounds__(256, 2) void conv_f8p(
    const unsigned char* __restrict__ act, const unsigned char* __restrict__ wp,
    const float* __restrict__ bias, unsigned char* __restrict__ outF,
    __hip_bfloat16* __restrict__ outB, int Cin, int Cout, int H, int W) {
  __shared__ __align__(16) unsigned char ApS[660 * 32];
  __shared__ __align__(16) unsigned char BwS[576 * 32];
  const int tid = threadIdx.x;
  const int lane = tid & 63;
  const int wv = tid >> 6;
  const int quad = lane >> 4, l15 = lane & 15;
  const int coB = Cout >> 6;
  const int n = blockIdx.z / coB;
  const int co0 = (blockIdx.z % coB) << 6;
  const int x0g = blockIdx.x << 6;
  const int y0 = blockIdx.y << 3;

  f32x4_t acc[8][4];
#pragma unroll
  for (int mt = 0; mt < 8; ++mt)
#pragma unroll
    for (int nt = 0; nt < 4; ++nt) acc[mt][nt] = (f32x4_t)0.0f;

  for (int cb = 0; cb < Cin; cb += 32) {
    for (int e = tid; e < 1320; e += 256) {
      int q = e & 1, pos = e >> 1;
      int r = pos / 66, c = pos - r * 66;
      int gy = y0 - 1 + r, gx = x0g - 1 + c;
      uint4 v = make_uint4(0, 0, 0, 0);
      if (gy >= 0 && gy < H && gx >= 0 && gx < W)
        v = *(const uint4*)(act + ((long)((long)n * H + gy) * W + gx) * Cin +
                            cb + q * 16);
      *(uint4*)&ApS[pos * 32 + q * 16] = v;
    }
    for (int e = tid; e < 1152; e += 256) {
      int q = e & 1, idx = e >> 1;
      int o = idx >> 6, co = idx & 63;
      *(uint4*)&BwS[idx * 32 + q * 16] =
          *(const uint4*)(wp + ((long)(o * Cout + co0 + co)) * Cin + cb +
                          q * 16);
    }
    __syncthreads();

#pragma unroll
    for (int o = 0; o < 9; ++o) {
      const int dy = o / 3, dx = o % 3;
      long long bf[4];
#pragma unroll
      for (int nt = 0; nt < 4; ++nt)
        bf[nt] = *(const long long*)&BwS[((o << 6) + nt * 16 + l15) * 32 +
                                         quad * 8];
#pragma unroll
      for (int mt = 0; mt < 8; ++mt) {
        const int rl = 2 * wv + (mt >> 2) + dy;
        const int pl = (mt & 3) * 16 + l15 + dx;
        const long long a =
            *(const long long*)&ApS[(rl * 66 + pl) * 32 + quad * 8];
#pragma unroll
        for (int nt = 0; nt < 4; ++nt)
          acc[mt][nt] = __builtin_amdgcn_mfma_f32_16x16x32_fp8_fp8(
              a, bf[nt], acc[mt][nt], 0, 0, 0);
      }
    }
    __syncthreads();
  }

  const int Ho = H >> 1, Wo = W >> 1;
  const int ho = (blockIdx.y << 2) + wv;
  float bv[4];
#pragma unroll
  for (int nt = 0; nt < 4; ++nt) bv[nt] = bias[co0 + nt * 16 + l15];
#pragma unroll
  for (int mtA = 0; mtA < 4; ++mtA)
#pragma unroll
    for (int nt = 0; nt < 4; ++nt) {
      const int col = co0 + nt * 16 + l15;
#pragma unroll
      for (int half = 0; half < 2; ++half) {
        float m0 = fmaxf(
            fmaxf(acc[mtA][nt][2 * half], acc[mtA][nt][2 * half + 1]),
            fmaxf(acc[mtA + 4][nt][2 * half], acc[mtA + 4][nt][2 * half + 1]));
        float v = fmaxf(m0 + bv[nt], 0.0f);
        int wo = (blockIdx.x << 5) + mtA * 8 + quad * 2 + half;
        long oi = (((long)n * Ho + ho) * Wo + wo) * Cout + col;
        outF[oi] = f2fp8(v);
        outB[oi] = __float2bfloat16(v);
      }
    }
}

// NHWC [j][Ho][Wo][C] -> col-major planar [(j*C+c)][Wo][Ho]. (r10-proven)
__global__ __launch_bounds__(256) void transpose_k(
    const __hip_bfloat16* __restrict__ in, __hip_bfloat16* __restrict__ out,
    int C, int Ho, int Wo) {
  const int cl = threadIdx.x & 31;
  const int wl = threadIdx.x >> 5;
  const int cg = C >> 5;
  const int j = blockIdx.z / cg;
  const int c = (blockIdx.z % cg) * 32 + cl;
  const int wo = blockIdx.x * 8 + wl;
  const int ho0 = blockIdx.y * 8;
  __align__(16) __hip_bfloat16 res[8];
#pragma unroll
  for (int i = 0; i < 8; ++i)
    res[i] = in[(((long)j * Ho + ho0 + i) * Wo + wo) * C + c];
  *(uint4*)&out[((long)(j * C + c) * Wo + wo) * Ho + ho0] =
      *(const uint4*)res;
}

// l_perc partial: sum |cur - gt| over 8*M8 bf16 elements -> slots[2]
__global__ __launch_bounds__(256) void perc_kernel(
    const __hip_bfloat16* __restrict__ gt, const __hip_bfloat16* __restrict__ cur,
    int M8, float* __restrict__ slots) {
  __shared__ float s4[4];
  const uint4* g4 = (const uint4*)gt;
  const uint4* c4 = (const uint4*)cur;
  float acc = 0.0f;
  for (int i = blockIdx.x * 256 + threadIdx.x; i < M8; i += gridDim.x * 256) {
    uint4 g = g4[i], c = c4[i];
    const unsigned* gu = (const unsigned*)&g;
    const unsigned* cu = (const unsigned*)&c;
#pragma unroll
    for (int k = 0; k < 4; ++k) {
      float g0 = __uint_as_float(gu[k] << 16);
      float g1 = __uint_as_float(gu[k] & 0xffff0000u);
      float c0 = __uint_as_float(cu[k] << 16);
      float c1 = __uint_as_float(cu[k] & 0xffff0000u);
      acc += fabsf(c0 - g0) + fabsf(c1 - g1);
    }
  }
  float r = blk_sum256(acc, s4);
  if (threadIdx.x == 0) atomicAdd(&slots[2], r);
}

// Style partial via bf16 MFMA (r5-proven). Inputs col-major planar bf16.
template <int BM>
__global__ __launch_bounds__(256) void gram_mfma(
    const __hip_bfloat16* __restrict__ gt_p,
    const __hip_bfloat16* __restrict__ cur_p, int Wp, int Hp, float fscale,
    float* __restrict__ slots) {
  constexpr int COLS = BM + 64;
  constexpr int WR = BM / 4;
  constexpr int MT = WR / 16;
  __shared__ __align__(16) short S[2 * COLS * 40];
  __shared__ float s4[4];
  const int tid = threadIdx.x;
  const int lane = tid & 63;
  const int wvi = tid >> 6;
  const int quad = lane >> 4, l15 = lane & 15;
  const int vt = blockIdx.x * 64;
  const int wt = blockIdx.y * BM;
  const long plane = (long)blockIdx.z * Wp * Hp;
  const __hip_bfloat16* bases[2] = {gt_p + plane, cur_p + plane};

  f32x4_t acc[2][MT][4];
#pragma unroll
  for (int t = 0; t < 2; ++t)
#pragma unroll
    for (int mt = 0; mt < MT; ++mt)
#pragma unroll
      for (int nt = 0; nt < 4; ++nt) acc[t][mt][nt] = (f32x4_t)0.0f;

  const int nchunk = 2 * COLS * 4;
  for (int h0 = 0; h0 < Hp; h0 += 32) {
    for (int e = tid; e < nchunk; e += 256) {
      int chunk = e & 3;
      int colt = e >> 2;
      int t = colt / COLS;
      int col = colt - t * COLS;
      int sc = (col < BM) ? (wt + col) : (vt + col - BM);
      uint4 v = *(const uint4*)(bases[t] + (long)sc * Hp + h0 + chunk * 8);
      *(uint4*)&S[(t * COLS + col) * 40 + chunk * 8] = v;
    }
    __syncthreads();
#pragma unroll
    for (int t = 0; t < 2; ++t) {
      bf16x8_t bf[4];
#pragma unroll
      for (int nt = 0; nt < 4; ++nt)
        bf[nt] = *(const bf16x8_t*)&S[(t * COLS + BM + nt * 16 + l15) * 40 +
                                      quad * 8];
#pragma unroll
      for (int mt = 0; mt < MT; ++mt) {
        bf16x8_t a = *(const bf16x8_t*)&S[(t * COLS + wvi * WR + mt * 16 + l15) *
                                              40 + quad * 8];
#pragma unroll
        for (int nt = 0; nt < 4; ++nt)
          acc[t][mt][nt] = __builtin_amdgcn_mfma_f32_16x16x32_bf16(
              a, bf[nt], acc[t][mt][nt], 0, 0, 0);
      }
    }
    __syncthreads();
  }

  float local = 0.0f;
#pragma unroll
  for (int mt = 0; mt < MT; ++mt)
#pragma unroll
    for (int nt = 0; nt < 4; ++nt)
#pragma unroll
      for (int reg = 0; reg < 4; ++reg)
        local += fabsf(acc[1][mt][nt][reg] - acc[0][mt][nt][reg]);
  float r = blk_sum256(local, s4);
  if (tid == 0) atomicAdd(&slots[3], r * fscale);
}

__global__ void combine_kernel(const float* __restrict__ slots,
                               float* __restrict__ out) {
  if (threadIdx.x == 0) {
    const float Nn = 1572864.0f;
    const float Nigt = 8388608.0f;
    out[0] = 2.0f * slots[0] / Nn + slots[1] / Nn + slots[2] / Nigt + slots[3];
  }
}

extern "C" void kernel_launch(void* const* d_in, const int* in_sizes, int n_in,
                              void* d_out, int out_size, void* d_ws,
                              size_t ws_size, hipStream_t stream) {
  (void)in_sizes; (void)n_in; (void)out_size;
  const float* igt = (const float*)d_in[0];
  const float* iout = (const float*)d_in[1];
  const float* mask = (const float*)d_in[2];
  const float* w[7];
  const float* b[7];
  for (int i = 0; i < 7; ++i) {
    w[i] = (const float*)d_in[3 + 2 * i];
    b[i] = (const float*)d_in[4 + 2 * i];
  }
  float* slots = (float*)d_ws;

  unsigned char* wpk = (unsigned char*)((char*)d_ws + 256);
  const long wpOff[6] = {0, 36864, 110592, 258048, 552960, 1142784};
  const int wpCin[6] = {64, 64, 128, 128, 256, 256};
  const int wpCout[6] = {64, 128, 128, 256, 256, 256};
  __hip_bfloat16* w1k = (__hip_bfloat16*)((char*)d_ws + 256 + 1732608);
  // weights end at byte 1,736,960

  const size_t NEED2 = 194674944ULL;  // 1,736,960 + 2*96,468,992
  const int NB = (ws_size >= NEED2) ? 2 : 1;
  const int B3 = 3 * NB;

  char* base = (char*)d_ws + 1736960;
  __hip_bfloat16* Apk = (__hip_bfloat16*)base;                              // NB*16.78MB
  unsigned char* Y1 = (unsigned char*)(base + (size_t)NB * 16777216);       // NB*16.78MB
  unsigned char* P1N8 = (unsigned char*)(base + (size_t)NB * 33554432);     // NB*12.58MB
  __hip_bfloat16* P1Nb = (__hip_bfloat16*)(base + (size_t)NB * 46137344);   // NB*8.39MB
  __hip_bfloat16* pgT1 = (__hip_bfloat16*)(base + (size_t)NB * 54525952);   // NB*8.39MB
  __hip_bfloat16* pcT1 = (__hip_bfloat16*)(base + (size_t)NB * 62914560);   // NB*8.39MB
  __hip_bfloat16* P2Nb = (__hip_bfloat16*)(base + (size_t)NB * 71303168);   // NB*12.58MB
  __hip_bfloat16* P2T = (__hip_bfloat16*)(base + (size_t)NB * 83886080);    // NB*12.58MB
  // Phase-M aliases (live ranges strictly sequential):
  unsigned char* T = (unsigned char*)base;                                  // over Apk/Y1
  unsigned char* P2N8 = (unsigned char*)(base + (size_t)NB * 46137344);     // over P1Nb
  unsigned char* Y5 = (unsigned char*)base;                                 // over T
  unsigned char* Y6 = (unsigned char*)(base + (size_t)NB * 12582912);
  __hip_bfloat16* P3Nb = (__hip_bfloat16*)(base + (size_t)NB * 33554432);   // over P1N8
  __hip_bfloat16* P3T = (__hip_bfloat16*)(base + (size_t)NB * 39845888);
  unsigned char* P3N8 = (unsigned char*)(base + (size_t)NB * 46137344);     // over dead P2N8

  const float fs1 = (float)(1.0 / (4194304.0 * 4096.0));
  const float fs2 = (float)(1.0 / (2097152.0 * 16384.0));
  const float fs3 = (float)(1.0 / (1048576.0 * 65536.0));

  init_slots<<<1, 64, 0, stream>>>(slots);
  l1_kernel<<<304, 256, 0, stream>>>(igt, iout, mask, slots);
  for (int l = 0; l < 6; ++l) {
    int elems = wpCout[l] * wpCin[l] * 9;
    pack_w<<<(elems + 255) / 256, 256, 0, stream>>>(w[l + 1], wpk + wpOff[l],
                                                    wpCin[l], wpCout[l]);
  }
  pack_w1<<<8, 256, 0, stream>>>(w[0], w1k);

  for (int n0 = 0; n0 < 2; n0 += NB) {
    // ---- per-stream front end: pack -> conv1 -> conv2+pool -> gram1 ----
    for (int s = 0; s < 3; ++s) {
      pack2_kernel<<<NB * 1024, 256, 0, stream>>>(igt, iout, mask, Apk, s, n0, NB);
      conv1m<<<dim3(8, 64, NB), 256, 0, stream>>>(Apk, w1k, b[0], Y1);
      conv_f8p<<<dim3(8, 64, NB), 256, 0, stream>>>(
          Y1, wpk + wpOff[0], b[1], P1N8 + (size_t)s * NB * 4194304, P1Nb,
          64, 64, 512, 512);
      transpose_k<<<dim3(32, 32, NB * 2), 256, 0, stream>>>(
          P1Nb, (s ? pcT1 : pgT1), 64, 256, 256);
      if (s > 0) {
        perc_kernel<<<304, 256, 0, stream>>>(pgT1, pcT1, NB * 524288, slots);
        gram_mfma<128><<<dim3(4, 2, NB * 64), 256, 0, stream>>>(
            pgT1, pcT1, 256, 256, fs1, slots);
      }
    }
    // ---- batched over 3NB images: conv3..conv7, perc/gram L2/L3 ----
    conv_f8<<<dim3(4, 32, B3 * 2), 256, 0, stream>>>(
        P1N8, wpk + wpOff[1], b[2], T, 64, 128, 256, 256);
    conv_f8p<<<dim3(4, 32, B3 * 2), 256, 0, stream>>>(
        T, wpk + wpOff[2], b[3], P2N8, P2Nb, 128, 128, 256, 256);
    transpose_k<<<dim3(16, 16, B3 * 4), 256, 0, stream>>>(P2Nb, P2T, 128, 128, 128);
    for (int s = 1; s <= 2; ++s) {
      perc_kernel<<<304, 256, 0, stream>>>(
          P2T, P2T + (size_t)s * NB * 2097152, NB * 262144, slots);
      gram_mfma<128><<<dim3(2, 1, NB * 128), 256, 0, stream>>>(
          P2T, P2T + (size_t)s * NB * 2097152, 128, 128, fs2, slots);
    }
    conv_f8<<<dim3(2, 16, B3 * 4), 256, 0, stream>>>(
        P2N8, wpk + wpOff[3], b[4], Y5, 128, 256, 128, 128);
    conv_f8<<<dim3(2, 16, B3 * 4), 256, 0, stream>>>(
        Y5, wpk + wpOff[4], b[5], Y6, 256, 256, 128, 128);
    conv_f8p<<<dim3(2, 16, B3 * 4), 256, 0, stream>>>(
        Y6, wpk + wpOff[5], b[6], P3N8, P3Nb, 256, 256, 128, 128);
    transpose_k<<<dim3(8, 8, B3 * 8), 256, 0, stream>>>(P3Nb, P3T, 256, 64, 64);
    for (int s = 1; s <= 2; ++s) {
      perc_kernel<<<304, 256, 0, stream>>>(
          P3T, P3T + (size_t)s * NB * 1048576, NB * 131072, slots);
      gram_mfma<64><<<dim3(1, 1, NB * 256), 256, 0, stream>>>(
          P3T, P3T + (size_t)s * NB * 1048576, 64, 64, fs3, slots);
    }
  }

  combine_kernel<<<1, 64, 0, stream>>>(slots, (float*)d_out);
}

// Round 12
// 953.164 us; speedup vs baseline: 1.9167x; 1.0296x over previous
//
#include <hip/hip_runtime.h>
#include <hip/hip_bf16.h>

// ---------------------------------------------------------------------------
// VGG16 perceptual+style inpainting loss.
// conv1: bf16 MFMA im2col-K32 -> fp8 (channel-permuted) output.
// conv2..7: fp8(e4m3) MFMA NHWC with K-PAIRED b128 LDS reads: activations
// stored with 64-channel groups permuted (pos = ((c>>3)&3)*16+((c>>5)&1)*8
// +(c&7)) so one ds_read_b128 feeds two K=32 MFMAs. A-fragments register-
// cached across dy. Pool epilogues dual-store fp8(perm) + bf16(logical).
// Gram: bf16 MFMA planar. Workspace layout identical to r11.
// ---------------------------------------------------------------------------

typedef __attribute__((ext_vector_type(8))) short bf16x8_t;
typedef __attribute__((ext_vector_type(4))) float f32x4_t;

__device__ __forceinline__ float b2f(__hip_bfloat16 v) {
  return __bfloat162float(v);
}

__device__ __forceinline__ unsigned char f2fp8(float v) {
  return (unsigned char)(__builtin_amdgcn_cvt_pk_fp8_f32(v, v, 0, false) & 0xff);
}

__device__ __forceinline__ int p64(int c) {  // channel -> stored position
  return ((c >> 3) & 3) * 16 + ((c >> 5) & 1) * 8 + (c & 7);
}

__device__ __forceinline__ float blk_sum256(float v, float* s4) {
#pragma unroll
  for (int o = 32; o > 0; o >>= 1) v += __shfl_down(v, o);
  int w = threadIdx.x >> 6;
  if ((threadIdx.x & 63) == 0) s4[w] = v;
  __syncthreads();
  float r = s4[0] + s4[1] + s4[2] + s4[3];
  __syncthreads();
  return r;
}

__global__ void init_slots(float* slots) {
  if (threadIdx.x < 8) slots[threadIdx.x] = 0.0f;
}

__global__ __launch_bounds__(256) void l1_kernel(
    const float* __restrict__ igt, const float* __restrict__ iout,
    const float* __restrict__ mask, float* __restrict__ slots) {
  __shared__ float s4[4];
  float ah = 0.0f, av = 0.0f;
  for (int idx = blockIdx.x * 256 + threadIdx.x; idx < 1572864;
       idx += gridDim.x * 256) {
    int pix = idx & 262143;
    int n = idx / 786432;
    float mk = mask[n * 262144 + pix];
    bool m = (mk != 0.0f);
    float d = fabsf(iout[idx] - igt[idx]);
    if (m) av += d; else ah += d;
  }
  float r = blk_sum256(ah, s4);
  if (threadIdx.x == 0) atomicAdd(&slots[0], r);
  r = blk_sum256(av, s4);
  if (threadIdx.x == 0) atomicAdd(&slots[1], r);
}

// Pack fp32 OIHW weights -> fp8 [tap][cout][cin-permuted] (conv2..7).
__global__ __launch_bounds__(256) void pack_w(const float* __restrict__ w,
                                              unsigned char* __restrict__ wp,
                                              int Cin, int Cout) {
  int i = blockIdx.x * 256 + threadIdx.x;
  if (i >= Cout * Cin * 9) return;
  int o = i % 9;
  int rem = i / 9;
  int ci = rem % Cin;
  int co = rem / Cin;
  int cis = (ci & ~63) + p64(ci & 63);
  wp[((long)(o * Cout + co)) * Cin + cis] = f2fp8(w[i]);
}

// Pack conv1 weights [64][3][3][3] OIHW -> bf16 [co][32], k=dy*9+dx*3+ci.
__global__ __launch_bounds__(256) void pack_w1(const float* __restrict__ w,
                                               __hip_bfloat16* __restrict__ wk) {
  int i = blockIdx.x * 256 + threadIdx.x;
  if (i >= 64 * 32) return;
  int co = i >> 5, k = i & 31;
  float v = 0.0f;
  if (k < 27) {
    int dy = k / 9, r = k - dy * 9;
    int dx = r / 3, ci = r - dx * 3;
    v = w[((co * 3 + ci) * 3 + dy) * 3 + dx];
  }
  wk[i] = __float2bfloat16(v);
}

// Build im2col-K32 bf16 input Apk[nl][y][x][32] for stream sid. (r10-proven)
__global__ __launch_bounds__(256) void pack2_kernel(
    const float* __restrict__ igt, const float* __restrict__ iout,
    const float* __restrict__ mask, __hip_bfloat16* __restrict__ apk, int sid,
    int n0, int NB) {
  int idx = blockIdx.x * 256 + threadIdx.x;
  if (idx >= NB * 262144) return;
  int nl = idx >> 18;
  int pix = idx & 262143;
  int y = pix >> 9, x = pix & 511;
  int sample = n0 + nl;
  __align__(16) __hip_bfloat16 buf[32];
#pragma unroll
  for (int k = 27; k < 32; ++k) buf[k] = __float2bfloat16(0.0f);
  for (int dy = 0; dy < 3; ++dy)
    for (int dx = 0; dx < 3; ++dx) {
      int gy = y - 1 + dy, gx = x - 1 + dx;
      bool inb = (gy >= 0 && gy < 512 && gx >= 0 && gx < 512);
      int p = gy * 512 + gx;
      bool useG;
      if (sid == 0) useG = true;
      else if (sid == 1) useG = false;
      else useG = inb && (mask[sample * 262144 + (inb ? p : 0)] != 0.0f);
      const float* src = useG ? igt : iout;
#pragma unroll
      for (int ci = 0; ci < 3; ++ci) {
        float v = inb ? src[sample * 786432 + ci * 262144 + p] : 0.0f;
        buf[dy * 9 + dx * 3 + ci] = __float2bfloat16(v);
      }
    }
  __hip_bfloat16* dst = apk + (long)idx * 32;
#pragma unroll
  for (int q = 0; q < 4; ++q)
    *(uint4*)&dst[q * 8] = *(const uint4*)&buf[q * 8];
}

// conv1: K=32 bf16 MFMA GEMM -> fp8 NHWC Y1 (permuted channel positions).
__global__ __launch_bounds__(256, 2) void conv1m(
    const __hip_bfloat16* __restrict__ apk, const __hip_bfloat16* __restrict__ wk,
    const float* __restrict__ bias, unsigned char* __restrict__ out) {
  __shared__ __align__(16) short ApS[512 * 32];
  __shared__ __align__(16) short BwS[64 * 32];
  const int tid = threadIdx.x;
  const int lane = tid & 63;
  const int wv = tid >> 6;
  const int quad = lane >> 4, l15 = lane & 15;
  const int n = blockIdx.z;
  const int x0 = blockIdx.x << 6;
  const int y0 = blockIdx.y << 3;

  for (int e = tid; e < 2048; e += 256) {
    int q = e & 3, pos = e >> 2;
    int r = pos >> 6, c = pos & 63;
    *(uint4*)&ApS[pos * 32 + q * 8] =
        *(const uint4*)(apk + (((long)n * 512 + y0 + r) * 512 + x0 + c) * 32 +
                        q * 8);
  }
  if (tid < 256) {
    int q = tid & 3, co = tid >> 2;
    *(uint4*)&BwS[co * 32 + q * 8] = *(const uint4*)(wk + co * 32 + q * 8);
  }
  __syncthreads();

  f32x4_t acc[8][4];
#pragma unroll
  for (int mt = 0; mt < 8; ++mt)
#pragma unroll
    for (int nt = 0; nt < 4; ++nt) acc[mt][nt] = (f32x4_t)0.0f;

  bf16x8_t bf[4];
#pragma unroll
  for (int nt = 0; nt < 4; ++nt)
    bf[nt] = *(const bf16x8_t*)&BwS[(nt * 16 + l15) * 32 + quad * 8];
#pragma unroll
  for (int mt = 0; mt < 8; ++mt) {
    const int rl = 2 * wv + (mt >> 2);
    const int pl = (mt & 3) * 16 + l15;
    const bf16x8_t a = *(const bf16x8_t*)&ApS[(rl * 64 + pl) * 32 + quad * 8];
#pragma unroll
    for (int nt = 0; nt < 4; ++nt)
      acc[mt][nt] = __builtin_amdgcn_mfma_f32_16x16x32_bf16(a, bf[nt],
                                                            acc[mt][nt], 0, 0, 0);
  }

  float bv[4];
#pragma unroll
  for (int nt = 0; nt < 4; ++nt) bv[nt] = bias[nt * 16 + l15];
#pragma unroll
  for (int mt = 0; mt < 8; ++mt) {
    const int y = y0 + 2 * wv + (mt >> 2);
#pragma unroll
    for (int nt = 0; nt < 4; ++nt) {
      const int colp = p64(nt * 16 + l15);
#pragma unroll
      for (int reg = 0; reg < 4; ++reg) {
        int px = (mt & 3) * 16 + quad * 4 + reg;
        float v = fmaxf(acc[mt][nt][reg] + bv[nt], 0.0f);
        out[(((long)n * 512 + y) * 512 + x0 + px) * 64 + colp] = f2fp8(v);
      }
    }
  }
}

// ---------------------------------------------------------------------------
// conv_f8 v2: fp8 MFMA 3x3 conv, K-paired b128 reads. Per-pixel LDS entry =
// 64B (one permuted 64-ch group): lane b128 at +quad*16 gives lo=k0..31
// fragment, hi=k32..63 fragment. A frags cached in regs across dy.
// Wave = 2 rows x 64 px x 64 co. LDS: A 42,240B + W 36,864B -> 2 blk/CU.
// ---------------------------------------------------------------------------
__global__ __launch_bounds__(256, 2) void conv_f8(
    const unsigned char* __restrict__ act, const unsigned char* __restrict__ wp,
    const float* __restrict__ bias, unsigned char* __restrict__ out, int Cin,
    int Cout, int H, int W) {
  __shared__ __align__(16) unsigned char ApS[660 * 64];
  __shared__ __align__(16) unsigned char BwS[576 * 64];
  const int tid = threadIdx.x;
  const int lane = tid & 63;
  const int wv = tid >> 6;
  const int quad = lane >> 4, l15 = lane & 15;
  const int coB = Cout >> 6;
  const int n = blockIdx.z / coB;
  const int co0 = (blockIdx.z % coB) << 6;
  const int x0 = blockIdx.x << 6;
  const int y0 = blockIdx.y << 3;

  f32x4_t acc[8][4];
#pragma unroll
  for (int mt = 0; mt < 8; ++mt)
#pragma unroll
    for (int nt = 0; nt < 4; ++nt) acc[mt][nt] = (f32x4_t)0.0f;

  for (int cb = 0; cb < Cin; cb += 64) {
    for (int e = tid; e < 2640; e += 256) {  // A: 660 px * 4 x 16B
      int q = e & 3, pos = e >> 2;
      int r = pos / 66, c = pos - r * 66;
      int gy = y0 - 1 + r, gx = x0 - 1 + c;
      uint4 v = make_uint4(0, 0, 0, 0);
      if (gy >= 0 && gy < H && gx >= 0 && gx < W)
        v = *(const uint4*)(act + ((long)((long)n * H + gy) * W + gx) * Cin +
                            cb + q * 16);
      *(uint4*)&ApS[pos * 64 + q * 16] = v;
    }
    for (int e = tid; e < 2304; e += 256) {  // W: 576 rows * 4 x 16B
      int q = e & 3, idx = e >> 2;
      int o = idx >> 6, co = idx & 63;
      *(uint4*)&BwS[idx * 64 + q * 16] =
          *(const uint4*)(wp + ((long)(o * Cout + co0 + co)) * Cin + cb +
                          q * 16);
    }
    __syncthreads();

#pragma unroll
    for (int dx = 0; dx < 3; ++dx) {
      uint4 F[4][4];
#pragma unroll
      for (int dr = 0; dr < 4; ++dr)
#pragma unroll
        for (int mc = 0; mc < 4; ++mc)
          F[dr][mc] = *(const uint4*)&ApS
              [((2 * wv + dr) * 66 + mc * 16 + l15 + dx) * 64 + quad * 16];
#pragma unroll
      for (int dy = 0; dy < 3; ++dy) {
        const int o = dy * 3 + dx;
        long long blo[4], bhi[4];
#pragma unroll
        for (int nt = 0; nt < 4; ++nt) {
          uint4 b4 = *(const uint4*)&BwS[((o << 6) + nt * 16 + l15) * 64 +
                                         quad * 16];
          blo[nt] = ((long long)b4.y << 32) | b4.x;
          bhi[nt] = ((long long)b4.w << 32) | b4.z;
        }
#pragma unroll
        for (int mt = 0; mt < 8; ++mt) {
          uint4 a4 = F[(mt >> 2) + dy][mt & 3];
          long long alo = ((long long)a4.y << 32) | a4.x;
          long long ahi = ((long long)a4.w << 32) | a4.z;
#pragma unroll
          for (int nt = 0; nt < 4; ++nt) {
            acc[mt][nt] = __builtin_amdgcn_mfma_f32_16x16x32_fp8_fp8(
                alo, blo[nt], acc[mt][nt], 0, 0, 0);
            acc[mt][nt] = __builtin_amdgcn_mfma_f32_16x16x32_fp8_fp8(
                ahi, bhi[nt], acc[mt][nt], 0, 0, 0);
          }
        }
      }
    }
    __syncthreads();
  }

  float bv[4];
#pragma unroll
  for (int nt = 0; nt < 4; ++nt) bv[nt] = bias[co0 + nt * 16 + l15];
#pragma unroll
  for (int mt = 0; mt < 8; ++mt) {
    const int y = y0 + 2 * wv + (mt >> 2);
#pragma unroll
    for (int nt = 0; nt < 4; ++nt) {
      const int colp = co0 + p64(nt * 16 + l15);
#pragma unroll
      for (int reg = 0; reg < 4; ++reg) {
        int px = (mt & 3) * 16 + quad * 4 + reg;
        float v = fmaxf(acc[mt][nt][reg] + bv[nt], 0.0f);
        out[(((long)n * H + y) * W + x0 + px) * Cout + colp] = f2fp8(v);
      }
    }
  }
}

// conv_f8p v2: conv_f8 + fused 2x2 maxpool; dual-store fp8(perm) + bf16(logical).
__global__ __launch_bounds__(256, 2) void conv_f8p(
    const unsigned char* __restrict__ act, const unsigned char* __restrict__ wp,
    const float* __restrict__ bias, unsigned char* __restrict__ outF,
    __hip_bfloat16* __restrict__ outB, int Cin, int Cout, int H, int W) {
  __shared__ __align__(16) unsigned char ApS[660 * 64];
  __shared__ __align__(16) unsigned char BwS[576 * 64];
  const int tid = threadIdx.x;
  const int lane = tid & 63;
  const int wv = tid >> 6;
  const int quad = lane >> 4, l15 = lane & 15;
  const int coB = Cout >> 6;
  const int n = blockIdx.z / coB;
  const int co0 = (blockIdx.z % coB) << 6;
  const int x0g = blockIdx.x << 6;
  const int y0 = blockIdx.y << 3;

  f32x4_t acc[8][4];
#pragma unroll
  for (int mt = 0; mt < 8; ++mt)
#pragma unroll
    for (int nt = 0; nt < 4; ++nt) acc[mt][nt] = (f32x4_t)0.0f;

  for (int cb = 0; cb < Cin; cb += 64) {
    for (int e = tid; e < 2640; e += 256) {
      int q = e & 3, pos = e >> 2;
      int r = pos / 66, c = pos - r * 66;
      int gy = y0 - 1 + r, gx = x0g - 1 + c;
      uint4 v = make_uint4(0, 0, 0, 0);
      if (gy >= 0 && gy < H && gx >= 0 && gx < W)
        v = *(const uint4*)(act + ((long)((long)n * H + gy) * W + gx) * Cin +
                            cb + q * 16);
      *(uint4*)&ApS[pos * 64 + q * 16] = v;
    }
    for (int e = tid; e < 2304; e += 256) {
      int q = e & 3, idx = e >> 2;
      int o = idx >> 6, co = idx & 63;
      *(uint4*)&BwS[idx * 64 + q * 16] =
          *(const uint4*)(wp + ((long)(o * Cout + co0 + co)) * Cin + cb +
                          q * 16);
    }
    __syncthreads();

#pragma unroll
    for (int dx = 0; dx < 3; ++dx) {
      uint4 F[4][4];
#pragma unroll
      for (int dr = 0; dr < 4; ++dr)
#pragma unroll
        for (int mc = 0; mc < 4; ++mc)
          F[dr][mc] = *(const uint4*)&ApS
              [((2 * wv + dr) * 66 + mc * 16 + l15 + dx) * 64 + quad * 16];
#pragma unroll
      for (int dy = 0; dy < 3; ++dy) {
        const int o = dy * 3 + dx;
        long long blo[4], bhi[4];
#pragma unroll
        for (int nt = 0; nt < 4; ++nt) {
          uint4 b4 = *(const uint4*)&BwS[((o << 6) + nt * 16 + l15) * 64 +
                                         quad * 16];
          blo[nt] = ((long long)b4.y << 32) | b4.x;
          bhi[nt] = ((long long)b4.w << 32) | b4.z;
        }
#pragma unroll
        for (int mt = 0; mt < 8; ++mt) {
          uint4 a4 = F[(mt >> 2) + dy][mt & 3];
          long long alo = ((long long)a4.y << 32) | a4.x;
          long long ahi = ((long long)a4.w << 32) | a4.z;
#pragma unroll
          for (int nt = 0; nt < 4; ++nt) {
            acc[mt][nt] = __builtin_amdgcn_mfma_f32_16x16x32_fp8_fp8(
                alo, blo[nt], acc[mt][nt], 0, 0, 0);
            acc[mt][nt] = __builtin_amdgcn_mfma_f32_16x16x32_fp8_fp8(
                ahi, bhi[nt], acc[mt][nt], 0, 0, 0);
          }
        }
      }
    }
    __syncthreads();
  }

  const int Ho = H >> 1, Wo = W >> 1;
  const int ho = (blockIdx.y << 2) + wv;
  float bv[4];
#pragma unroll
  for (int nt = 0; nt < 4; ++nt) bv[nt] = bias[co0 + nt * 16 + l15];
#pragma unroll
  for (int mtA = 0; mtA < 4; ++mtA)
#pragma unroll
    for (int nt = 0; nt < 4; ++nt) {
      const int col = co0 + nt * 16 + l15;
      const int colp = co0 + p64(nt * 16 + l15);
#pragma unroll
      for (int half = 0; half < 2; ++half) {
        float m0 = fmaxf(
            fmaxf(acc[mtA][nt][2 * half], acc[mtA][nt][2 * half + 1]),
            fmaxf(acc[mtA + 4][nt][2 * half], acc[mtA + 4][nt][2 * half + 1]));
        float v = fmaxf(m0 + bv[nt], 0.0f);
        int wo = (blockIdx.x << 5) + mtA * 8 + quad * 2 + half;
        long rowbase = (((long)n * Ho + ho) * Wo + wo) * Cout;
        outF[rowbase + colp] = f2fp8(v);
        outB[rowbase + col] = __float2bfloat16(v);
      }
    }
}

// NHWC [j][Ho][Wo][C] -> col-major planar [(j*C+c)][Wo][Ho]. (r10-proven)
__global__ __launch_bounds__(256) void transpose_k(
    const __hip_bfloat16* __restrict__ in, __hip_bfloat16* __restrict__ out,
    int C, int Ho, int Wo) {
  const int cl = threadIdx.x & 31;
  const int wl = threadIdx.x >> 5;
  const int cg = C >> 5;
  const int j = blockIdx.z / cg;
  const int c = (blockIdx.z % cg) * 32 + cl;
  const int wo = blockIdx.x * 8 + wl;
  const int ho0 = blockIdx.y * 8;
  __align__(16) __hip_bfloat16 res[8];
#pragma unroll
  for (int i = 0; i < 8; ++i)
    res[i] = in[(((long)j * Ho + ho0 + i) * Wo + wo) * C + c];
  *(uint4*)&out[((long)(j * C + c) * Wo + wo) * Ho + ho0] =
      *(const uint4*)res;
}

// l_perc partial: sum |cur - gt| over 8*M8 bf16 elements -> slots[2]
__global__ __launch_bounds__(256) void perc_kernel(
    const __hip_bfloat16* __restrict__ gt, const __hip_bfloat16* __restrict__ cur,
    int M8, float* __restrict__ slots) {
  __shared__ float s4[4];
  const uint4* g4 = (const uint4*)gt;
  const uint4* c4 = (const uint4*)cur;
  float acc = 0.0f;
  for (int i = blockIdx.x * 256 + threadIdx.x; i < M8; i += gridDim.x * 256) {
    uint4 g = g4[i], c = c4[i];
    const unsigned* gu = (const unsigned*)&g;
    const unsigned* cu = (const unsigned*)&c;
#pragma unroll
    for (int k = 0; k < 4; ++k) {
      float g0 = __uint_as_float(gu[k] << 16);
      float g1 = __uint_as_float(gu[k] & 0xffff0000u);
      float c0 = __uint_as_float(cu[k] << 16);
      float c1 = __uint_as_float(cu[k] & 0xffff0000u);
      acc += fabsf(c0 - g0) + fabsf(c1 - g1);
    }
  }
  float r = blk_sum256(acc, s4);
  if (threadIdx.x == 0) atomicAdd(&slots[2], r);
}

// Style partial via bf16 MFMA (r5-proven). Inputs col-major planar bf16.
template <int BM>
__global__ __launch_bounds__(256) void gram_mfma(
    const __hip_bfloat16* __restrict__ gt_p,
    const __hip_bfloat16* __restrict__ cur_p, int Wp, int Hp, float fscale,
    float* __restrict__ slots) {
  constexpr int COLS = BM + 64;
  constexpr int WR = BM / 4;
  constexpr int MT = WR / 16;
  __shared__ __align__(16) short S[2 * COLS * 40];
  __shared__ float s4[4];
  const int tid = threadIdx.x;
  const int lane = tid & 63;
  const int wvi = tid >> 6;
  const int quad = lane >> 4, l15 = lane & 15;
  const int vt = blockIdx.x * 64;
  const int wt = blockIdx.y * BM;
  const long plane = (long)blockIdx.z * Wp * Hp;
  const __hip_bfloat16* bases[2] = {gt_p + plane, cur_p + plane};

  f32x4_t acc[2][MT][4];
#pragma unroll
  for (int t = 0; t < 2; ++t)
#pragma unroll
    for (int mt = 0; mt < MT; ++mt)
#pragma unroll
      for (int nt = 0; nt < 4; ++nt) acc[t][mt][nt] = (f32x4_t)0.0f;

  const int nchunk = 2 * COLS * 4;
  for (int h0 = 0; h0 < Hp; h0 += 32) {
    for (int e = tid; e < nchunk; e += 256) {
      int chunk = e & 3;
      int colt = e >> 2;
      int t = colt / COLS;
      int col = colt - t * COLS;
      int sc = (col < BM) ? (wt + col) : (vt + col - BM);
      uint4 v = *(const uint4*)(bases[t] + (long)sc * Hp + h0 + chunk * 8);
      *(uint4*)&S[(t * COLS + col) * 40 + chunk * 8] = v;
    }
    __syncthreads();
#pragma unroll
    for (int t = 0; t < 2; ++t) {
      bf16x8_t bf[4];
#pragma unroll
      for (int nt = 0; nt < 4; ++nt)
        bf[nt] = *(const bf16x8_t*)&S[(t * COLS + BM + nt * 16 + l15) * 40 +
                                      quad * 8];
#pragma unroll
      for (int mt = 0; mt < MT; ++mt) {
        bf16x8_t a = *(const bf16x8_t*)&S[(t * COLS + wvi * WR + mt * 16 + l15) *
                                              40 + quad * 8];
#pragma unroll
        for (int nt = 0; nt < 4; ++nt)
          acc[t][mt][nt] = __builtin_amdgcn_mfma_f32_16x16x32_bf16(
              a, bf[nt], acc[t][mt][nt], 0, 0, 0);
      }
    }
    __syncthreads();
  }

  float local = 0.0f;
#pragma unroll
  for (int mt = 0; mt < MT; ++mt)
#pragma unroll
    for (int nt = 0; nt < 4; ++nt)
#pragma unroll
      for (int reg = 0; reg < 4; ++reg)
        local += fabsf(acc[1][mt][nt][reg] - acc[0][mt][nt][reg]);
  float r = blk_sum256(local, s4);
  if (tid == 0) atomicAdd(&slots[3], r * fscale);
}

__global__ void combine_kernel(const float* __restrict__ slots,
                               float* __restrict__ out) {
  if (threadIdx.x == 0) {
    const float Nn = 1572864.0f;
    const float Nigt = 8388608.0f;
    out[0] = 2.0f * slots[0] / Nn + slots[1] / Nn + slots[2] / Nigt + slots[3];
  }
}

extern "C" void kernel_launch(void* const* d_in, const int* in_sizes, int n_in,
                              void* d_out, int out_size, void* d_ws,
                              size_t ws_size, hipStream_t stream) {
  (void)in_sizes; (void)n_in; (void)out_size;
  const float* igt = (const float*)d_in[0];
  const float* iout = (const float*)d_in[1];
  const float* mask = (const float*)d_in[2];
  const float* w[7];
  const float* b[7];
  for (int i = 0; i < 7; ++i) {
    w[i] = (const float*)d_in[3 + 2 * i];
    b[i] = (const float*)d_in[4 + 2 * i];
  }
  float* slots = (float*)d_ws;

  unsigned char* wpk = (unsigned char*)((char*)d_ws + 256);
  const long wpOff[6] = {0, 36864, 110592, 258048, 552960, 1142784};
  const int wpCin[6] = {64, 64, 128, 128, 256, 256};
  const int wpCout[6] = {64, 128, 128, 256, 256, 256};
  __hip_bfloat16* w1k = (__hip_bfloat16*)((char*)d_ws + 256 + 1732608);
  // weights end at byte 1,736,960

  const size_t NEED2 = 194674944ULL;
  const int NB = (ws_size >= NEED2) ? 2 : 1;
  const int B3 = 3 * NB;

  char* base = (char*)d_ws + 1736960;
  __hip_bfloat16* Apk = (__hip_bfloat16*)base;
  unsigned char* Y1 = (unsigned char*)(base + (size_t)NB * 16777216);
  unsigned char* P1N8 = (unsigned char*)(base + (size_t)NB * 33554432);
  __hip_bfloat16* P1Nb = (__hip_bfloat16*)(base + (size_t)NB * 46137344);
  __hip_bfloat16* pgT1 = (__hip_bfloat16*)(base + (size_t)NB * 54525952);
  __hip_bfloat16* pcT1 = (__hip_bfloat16*)(base + (size_t)NB * 62914560);
  __hip_bfloat16* P2Nb = (__hip_bfloat16*)(base + (size_t)NB * 71303168);
  __hip_bfloat16* P2T = (__hip_bfloat16*)(base + (size_t)NB * 83886080);
  unsigned char* T = (unsigned char*)base;
  unsigned char* P2N8 = (unsigned char*)(base + (size_t)NB * 46137344);
  unsigned char* Y5 = (unsigned char*)base;
  unsigned char* Y6 = (unsigned char*)(base + (size_t)NB * 12582912);
  __hip_bfloat16* P3Nb = (__hip_bfloat16*)(base + (size_t)NB * 33554432);
  __hip_bfloat16* P3T = (__hip_bfloat16*)(base + (size_t)NB * 39845888);
  unsigned char* P3N8 = (unsigned char*)(base + (size_t)NB * 46137344);

  const float fs1 = (float)(1.0 / (4194304.0 * 4096.0));
  const float fs2 = (float)(1.0 / (2097152.0 * 16384.0));
  const float fs3 = (float)(1.0 / (1048576.0 * 65536.0));

  init_slots<<<1, 64, 0, stream>>>(slots);
  l1_kernel<<<304, 256, 0, stream>>>(igt, iout, mask, slots);
  for (int l = 0; l < 6; ++l) {
    int elems = wpCout[l] * wpCin[l] * 9;
    pack_w<<<(elems + 255) / 256, 256, 0, stream>>>(w[l + 1], wpk + wpOff[l],
                                                    wpCin[l], wpCout[l]);
  }
  pack_w1<<<8, 256, 0, stream>>>(w[0], w1k);

  for (int n0 = 0; n0 < 2; n0 += NB) {
    for (int s = 0; s < 3; ++s) {
      pack2_kernel<<<NB * 1024, 256, 0, stream>>>(igt, iout, mask, Apk, s, n0, NB);
      conv1m<<<dim3(8, 64, NB), 256, 0, stream>>>(Apk, w1k, b[0], Y1);
      conv_f8p<<<dim3(8, 64, NB), 256, 0, stream>>>(
          Y1, wpk + wpOff[0], b[1], P1N8 + (size_t)s * NB * 4194304, P1Nb,
          64, 64, 512, 512);
      transpose_k<<<dim3(32, 32, NB * 2), 256, 0, stream>>>(
          P1Nb, (s ? pcT1 : pgT1), 64, 256, 256);
      if (s > 0) {
        perc_kernel<<<304, 256, 0, stream>>>(pgT1, pcT1, NB * 524288, slots);
        gram_mfma<128><<<dim3(4, 2, NB * 64), 256, 0, stream>>>(
            pgT1, pcT1, 256, 256, fs1, slots);
      }
    }
    conv_f8<<<dim3(4, 32, B3 * 2), 256, 0, stream>>>(
        P1N8, wpk + wpOff[1], b[2], T, 64, 128, 256, 256);
    conv_f8p<<<dim3(4, 32, B3 * 2), 256, 0, stream>>>(
        T, wpk + wpOff[2], b[3], P2N8, P2Nb, 128, 128, 256, 256);
    transpose_k<<<dim3(16, 16, B3 * 4), 256, 0, stream>>>(P2Nb, P2T, 128, 128, 128);
    for (int s = 1; s <= 2; ++s) {
      perc_kernel<<<304, 256, 0, stream>>>(
          P2T, P2T + (size_t)s * NB * 2097152, NB * 262144, slots);
      gram_mfma<128><<<dim3(2, 1, NB * 128), 256, 0, stream>>>(
          P2T, P2T + (size_t)s * NB * 2097152, 128, 128, fs2, slots);
    }
    conv_f8<<<dim3(2, 16, B3 * 4), 256, 0, stream>>>(
        P2N8, wpk + wpOff[3], b[4], Y5, 128, 256, 128, 128);
    conv_f8<<<dim3(2, 16, B3 * 4), 256, 0, stream>>>(
        Y5, wpk + wpOff[4], b[5], Y6, 256, 256, 128, 128);
    conv_f8p<<<dim3(2, 16, B3 * 4), 256, 0, stream>>>(
        Y6, wpk + wpOff[5], b[6], P3N8, P3Nb, 256, 256, 128, 128);
    transpose_k<<<dim3(8, 8, B3 * 8), 256, 0, stream>>>(P3Nb, P3T, 256, 64, 64);
    for (int s = 1; s <= 2; ++s) {
      perc_kernel<<<304, 256, 0, stream>>>(
          P3T, P3T + (size_t)s * NB * 1048576, NB * 131072, slots);
      gram_mfma<64><<<dim3(1, 1, NB * 256), 256, 0, stream>>>(
          P3T, P3T + (size_t)s * NB * 1048576, 64, 64, fs3, slots);
    }
  }

  combine_kernel<<<1, 64, 0, stream>>>(slots, (float*)d_out);
}